// Round 9
// baseline (3902.629 us; speedup 1.0000x reference)
//
#include <hip/hip_runtime.h>

#define NG 8192
#define LN_EPS 1e-5f

typedef float v2f __attribute__((ext_vector_type(2)));

// ---------------- DPP wave-scan helpers (VALU-only, no LDS pipe) ----------------

__device__ __forceinline__ float wscan_add(float x) {
  x += __int_as_float(__builtin_amdgcn_update_dpp(0, __float_as_int(x), 0x111, 0xF, 0xF, true));
  x += __int_as_float(__builtin_amdgcn_update_dpp(0, __float_as_int(x), 0x112, 0xF, 0xF, true));
  x += __int_as_float(__builtin_amdgcn_update_dpp(0, __float_as_int(x), 0x114, 0xF, 0xF, true));
  x += __int_as_float(__builtin_amdgcn_update_dpp(0, __float_as_int(x), 0x118, 0xF, 0xF, true));
  x += __int_as_float(__builtin_amdgcn_update_dpp(0, __float_as_int(x), 0x142, 0xA, 0xF, false));
  x += __int_as_float(__builtin_amdgcn_update_dpp(0, __float_as_int(x), 0x143, 0xC, 0xF, false));
  return x;
}

__device__ __forceinline__ int wscan_max(int x) {
  int t;
  t = __builtin_amdgcn_update_dpp(0, x, 0x111, 0xF, 0xF, true); x = max(x, t);
  t = __builtin_amdgcn_update_dpp(0, x, 0x112, 0xF, 0xF, true); x = max(x, t);
  t = __builtin_amdgcn_update_dpp(0, x, 0x114, 0xF, 0xF, true); x = max(x, t);
  t = __builtin_amdgcn_update_dpp(0, x, 0x118, 0xF, 0xF, true); x = max(x, t);
  t = __builtin_amdgcn_update_dpp(0, x, 0x142, 0xA, 0xF, false); x = max(x, t);
  t = __builtin_amdgcn_update_dpp(0, x, 0x143, 0xC, 0xF, false); x = max(x, t);
  return x;
}

// ---------------- misc helpers ----------------

__device__ __forceinline__ void stage4(float* dst, const float* __restrict__ src,
                                       int n4, int tid, int nt) {
  float4* d = (float4*)dst;
  const float4* s = (const float4*)src;
  for (int t = tid; t < n4; t += nt) d[t] = s[t];
}

__device__ __forceinline__ void load20v(const float* __restrict__ p, v2f v[10]) {
  const float4* q = (const float4*)p;
#pragma unroll
  for (int t = 0; t < 5; t++) {
    float4 f = q[t];
    v[2*t]   = (v2f){f.x, f.y};
    v[2*t+1] = (v2f){f.z, f.w};
  }
}

__device__ __forceinline__ void store20v(float* __restrict__ p, const v2f v[10]) {
  float4* q = (float4*)p;
#pragma unroll
  for (int t = 0; t < 5; t++)
    q[t] = make_float4(v[2*t].x, v[2*t].y, v[2*t+1].x, v[2*t+1].y);
}

__device__ __forceinline__ float elem(const v2f* a, int k) { return a[k >> 1][k & 1]; }

// LN(relu(relu(h1)@W2+b2)@W3+b3)*g+be — packed fp32 pairs. Works for both
// global (SGPR s_load) and LDS (broadcast ds_read) weight pointers (inlined).
__device__ __forceinline__ void mlp23_ln1(
    const float* __restrict__ W2, const float* __restrict__ b2,
    const float* __restrict__ W3, const float* __restrict__ b3,
    const float* __restrict__ g,  const float* __restrict__ be,
    const v2f h1[10], v2f out[10]) {
  const v2f* W2v = (const v2f*)W2; const v2f* b2v = (const v2f*)b2;
  const v2f* W3v = (const v2f*)W3; const v2f* b3v = (const v2f*)b3;
  const v2f* gv  = (const v2f*)g;  const v2f* bev = (const v2f*)be;
  v2f h2[10];
#pragma unroll
  for (int j = 0; j < 10; j++) h2[j] = b2v[j];
#pragma unroll
  for (int k = 0; k < 20; k++) {
    float a = fmaxf(elem(h1, k), 0.0f); v2f av = {a, a};
#pragma unroll
    for (int j = 0; j < 10; j++) h2[j] += av * W2v[k*10 + j];
  }
  v2f h3[10];
#pragma unroll
  for (int j = 0; j < 10; j++) h3[j] = b3v[j];
#pragma unroll
  for (int k = 0; k < 20; k++) {
    float a = fmaxf(elem(h2, k), 0.0f); v2f av = {a, a};
#pragma unroll
    for (int j = 0; j < 10; j++) h3[j] += av * W3v[k*10 + j];
  }
  float mu = 0.0f;
#pragma unroll
  for (int j = 0; j < 10; j++) mu += h3[j].x + h3[j].y;
  mu *= 0.05f;
  float var = 0.0f;
#pragma unroll
  for (int j = 0; j < 10; j++) {
    float dx = h3[j].x - mu, dy = h3[j].y - mu;
    var += dx*dx + dy*dy;
  }
  var *= 0.05f;
  float rs = rsqrtf(var + LN_EPS);
  v2f muv = {mu, mu}, rsv = {rs, rs};
#pragma unroll
  for (int j = 0; j < 10; j++) out[j] = (h3[j] - muv) * rsv * gv[j] + bev[j];
}

// ---------------- kernels ----------------

__global__ __launch_bounds__(256) void k_prelayer(
    float* __restrict__ u, float* __restrict__ part, float* __restrict__ gu,
    const float* __restrict__ nmb1, const float* __restrict__ gpb1) {
  int t = blockIdx.x * 256 + threadIdx.x;   // NG*80 threads
  part[t] = 0.0f;
  if (t < NG * 40) {
    int j = t % 40;
    gu[t] = (j < 20) ? nmb1[j] : gpb1[j - 20];
  }
  if (t < NG * 20) u[t] = 0.0f;
}

// One-time weight packer: per layer l, blob of 2560 floats =
// [nmW1x 400][nmW2 400][nmW3 400][nmb2 20][nmb3 20][nmg 20][nmbe 20] (=1280)
// [gpW1x 400][gpW2 400][gpW3 400][gpb2 20][gpb3 20][gpg 20][gpbe 20] (=1280)
__global__ __launch_bounds__(256) void k_pack(
    float* __restrict__ wp,
    const float* __restrict__ nmW1, const float* __restrict__ nmW2,
    const float* __restrict__ nmW3, const float* __restrict__ nmb2,
    const float* __restrict__ nmb3, const float* __restrict__ nmg,
    const float* __restrict__ nmbe,
    const float* __restrict__ gpW1, const float* __restrict__ gpW2,
    const float* __restrict__ gpW3, const float* __restrict__ gpb2,
    const float* __restrict__ gpb3, const float* __restrict__ gpg,
    const float* __restrict__ gpbe) {
  int t = blockIdx.x * 256 + threadIdx.x;
  if (t >= 20 * 2560) return;
  int l = t / 2560, r = t % 2560;
  int half = (r >= 1280) ? 1 : 0;
  int rr = r - half * 1280;
  float v;
  if (rr < 400)       v = (half ? gpW1 : nmW1)[l * 800 + rr];       // x-rows only
  else if (rr < 800)  v = (half ? gpW2 : nmW2)[l * 400 + rr - 400];
  else if (rr < 1200) v = (half ? gpW3 : nmW3)[l * 400 + rr - 800];
  else if (rr < 1220) v = (half ? gpb2 : nmb2)[l * 20 + rr - 1200];
  else if (rr < 1240) v = (half ? gpb3 : nmb3)[l * 20 + rr - 1220];
  else if (rr < 1260) v = (half ? gpg  : nmg )[l * 20 + rr - 1240];
  else                v = (half ? gpbe : nmbe)[l * 20 + rr - 1260];
  wp[t] = v;
}

__global__ __launch_bounds__(256) void k_init(
    const float* __restrict__ xin, float* __restrict__ xs,
    const float* __restrict__ W1, const float* __restrict__ b1,
    const float* __restrict__ W2, const float* __restrict__ b2,
    const float* __restrict__ W3, const float* __restrict__ b3,
    const float* __restrict__ gw, const float* __restrict__ bw, int n) {
  int i = blockIdx.x * 256 + threadIdx.x;
  if (i >= n) return;
  float xi[10];
  const float2* xp = (const float2*)(xin + (size_t)i * 10);
#pragma unroll
  for (int t = 0; t < 5; t++) { float2 f = xp[t]; xi[t*2] = f.x; xi[t*2+1] = f.y; }
  const v2f* W1v = (const v2f*)W1; const v2f* b1v = (const v2f*)b1;
  v2f h1[10];
#pragma unroll
  for (int j = 0; j < 10; j++) h1[j] = b1v[j];
#pragma unroll
  for (int k = 0; k < 10; k++) {
    float a = xi[k]; v2f av = {a, a};
#pragma unroll
    for (int j = 0; j < 10; j++) h1[j] += av * W1v[k*10 + j];
  }
  v2f out[10];
  mlp23_ln1(W2, b2, W3, b3, gw, bw, h1, out);
  store20v(xs + (size_t)i * 20, out);
}

// Per-layer node kernel — GRID-STRIDE over 256-node tiles with grid=1792
// (= measured 7 blocks/CU capacity x 256 CUs). Rationale (rounds 5-8):
// residency is capped at ~7 blocks/CU by something source-level SGPR caps
// cannot move (112/96/80 all gave 7); a 1954-block grid therefore ran a
// SECOND full-latency generation of 162 blocks at 0.6 blocks/CU — half the
// wall at 8% utilization. Fix: fit the grid to capacity; extra tiles become
// warm second iterations of resident blocks: weights stay staged (barrier
// outside the loop) and the next tile's batch key + x rows are prefetched
// during the current tile's pre-aggr MLP + scan (~1500 cy of cover). The
// prefetch reuses x[10] (dead after the residual) -> no VGPR growth past
// the 64-reg / 8-wave cliff.
// Weight split unchanged: nm weights stream via s_load (SGPR operands),
// gp blob staged once into LDS (broadcast ds_read, conflict-free).
// Aggregation: deterministic DPP scan + run-end slot stores (no atomics);
// slot indexing is node-space-based so grid-stride doesn't affect it.
__global__ __launch_bounds__(256) __attribute__((amdgpu_num_sgpr(80)))
void k_node(
    const int* __restrict__ batch, float* __restrict__ xs,
    float* __restrict__ ws, const float* __restrict__ wl, int n) {
  float* part = ws;                         // NG*80
  const float* gu = ws + NG * 80;           // NG*40
  __shared__ float sm[1280];
  int tid = threadIdx.x;
  int lane = tid & 63;
  int ntiles = (n + 255) >> 8;

  // tile-0 prefetch ABOVE the staging barrier: batch->gu is the longest
  // dependent chain; issue it so gu can start right after the barrier.
  int tile = blockIdx.x;
  int i = tile * 256 + tid;
  bool valid = i < n;
  int ic = valid ? i : (n - 1);
  int b = batch[ic];
  v2f x[10];
  load20v(xs + (size_t)ic * 20, x);

  stage4(sm, wl + 1280, 320, tid, 256);     // whole gp blob, contiguous
  __syncthreads();

  for (;;) {
    // ---- NodeModel: h1 = x@W1x + gu_nm[b]  (gu = u@W1u + b1, prefolded) ----
    v2f h1[10];
    load20v(gu + (size_t)b * 40, h1);
    const v2f* W1v = (const v2f*)wl;
#pragma unroll
    for (int k = 0; k < 20; k++) {
      float a = elem(x, k); v2f av = {a, a};
#pragma unroll
      for (int j = 0; j < 10; j++) h1[j] += av * W1v[k*10 + j];
    }
    v2f xn[10];
    mlp23_ln1(wl + 400, wl + 1200, wl + 800, wl + 1220, wl + 1240, wl + 1260,
              h1, xn);
#pragma unroll
    for (int j = 0; j < 10; j++) xn[j] += x[j];   // residual; x DEAD after this
    if (valid) store20v(xs + (size_t)ic * 20, xn);

    // ---- software pipeline: prefetch NEXT tile's key + x into the dead x[10]
    int ntile = tile + gridDim.x;
    bool more = ntile < ntiles;
    int ni = ntile * 256 + tid;
    bool nvalid = more && (ni < n);
    int nic = nvalid ? ni : (n - 1);
    int nb = 0;
    if (more) {
      nb = batch[nic];
      load20v(xs + (size_t)nic * 20, x);          // rows owned by this block's
    }                                             // next tile; not yet updated

    // ---- pre-aggr MLP on updated x (weights from LDS broadcast) ----
    v2f p1[10];
    load20v(gu + (size_t)b * 40 + 20, p1);
    const v2f* G1v = (const v2f*)sm;
#pragma unroll
    for (int k = 0; k < 20; k++) {
      float a = elem(xn, k); v2f av = {a, a};
#pragma unroll
      for (int j = 0; j < 10; j++) p1[j] += av * G1v[k*10 + j];
    }
    v2f pre[10];
    mlp23_ln1(sm + 400, sm + 1200, sm + 800, sm + 1220, sm + 1240, sm + 1260,
              p1, pre);

    // ---- aggregation: DPP scan + run-end slot stores (batch sorted) ----
    int key = valid ? b : -1;
    if (!valid) {
#pragma unroll
      for (int j = 0; j < 10; j++) pre[j] = (v2f){0.0f, 0.0f};
    }
    int pk = __builtin_amdgcn_update_dpp(-1, key, 0x138, 0xF, 0xF, false);
    int nk = __builtin_amdgcn_update_dpp(-2, key, 0x130, 0xF, 0xF, false);
    bool isstart = (key != pk);
    int st = wscan_max(isstart ? lane : 0);   // start lane of my run

#pragma unroll
    for (int j = 0; j < 10; j++) {
      pre[j].x = wscan_add(pre[j].x);
      pre[j].y = wscan_add(pre[j].y);
    }

    int pl = (st > 0) ? (st - 1) : 0;
    float use = (st > 0) ? 1.0f : 0.0f;
    v2f fl[10];
#pragma unroll
    for (int j = 0; j < 10; j++) {
      float bx = __shfl(pre[j].x, pl);
      float by = __shfl(pre[j].y, pl);
      fl[j].x = pre[j].x - use * bx;
      fl[j].y = pre[j].y - use * by;
    }
    bool runend = valid && (nk != key);       // lane63 gets nk=-2 -> true
    if (runend) {
      int slot = (i >> 6) & 3;                // graphs span <=4 consecutive waves
      float* pp = part + (size_t)b * 80 + slot * 20;
#pragma unroll
      for (int j = 0; j < 10; j++) {
        pp[2*j]     = fl[j].x;
        pp[2*j + 1] = fl[j].y;
      }
    }

    if (!more) break;
    tile = ntile; i = ni; valid = nvalid; ic = nic; b = nb;
  }
}

// Per-layer global kernel, 4 LANES PER GRAPH (NG*4 threads): coalesced slot
// loads, fixed-tree shfl butterflies, transposed weights in LDS. No slot
// re-zero needed — batch is constant across layers, so exactly the same
// (graph, slot) pairs are rewritten every layer; slots never written stay
// at their k_prelayer zeros.
__global__ __launch_bounds__(128) void k_global(
    float* __restrict__ u, float* __restrict__ part, float* __restrict__ gu,
    const float* __restrict__ qW1, const float* __restrict__ qb1,
    const float* __restrict__ qW2, const float* __restrict__ qb2,
    const float* __restrict__ qW3, const float* __restrict__ qb3,
    const float* __restrict__ qg,  const float* __restrict__ qbe,
    const float* __restrict__ nmW1u, const float* __restrict__ nmb1n,
    const float* __restrict__ gpW1u, const float* __restrict__ gpb1n,
    int has_next) {
  __shared__ float sW1T[20 * 40];   // [j][k], k over (agg | u)
  __shared__ float sW2T[20 * 20];   // [j][k]
  __shared__ float sW3T[20 * 20];
  __shared__ float sNT[20 * 20];    // nmW1u^T (next layer)
  __shared__ float sGT[20 * 20];    // gpW1u^T (next layer)
  __shared__ float sB[140];         // qb1|qb2|qb3|qg|qbe|nmb1n|gpb1n
  int tid = threadIdx.x;
  for (int e = tid; e < 800; e += 128) sW1T[(e % 20) * 40 + (e / 20)] = qW1[e];
  for (int e = tid; e < 400; e += 128) {
    int k = e / 20, j = e % 20;
    sW2T[j * 20 + k] = qW2[e];
    sW3T[j * 20 + k] = qW3[e];
    sNT[j * 20 + k]  = nmW1u[e];
    sGT[j * 20 + k]  = gpW1u[e];
  }
  if (tid < 20) {
    sB[tid]       = qb1[tid];
    sB[20 + tid]  = qb2[tid];
    sB[40 + tid]  = qb3[tid];
    sB[60 + tid]  = qg[tid];
    sB[80 + tid]  = qbe[tid];
    sB[100 + tid] = nmb1n[tid];
    sB[120 + tid] = gpb1n[tid];
  }
  __syncthreads();

  int t = blockIdx.x * 128 + tid;   // exactly NG*4 threads
  int g = t >> 2;                   // graph
  int q = t & 3;                    // quarter: output cols [q*5, q*5+5)
  int lane = tid & 63;
  int gl = lane & ~3;               // group base lane (groups never cross waves)

  // my partial slot (coalesced 80B/lane), then fixed-tree butterfly sum
  float a[20];
  {
    const float4* p = (const float4*)(part + (size_t)g * 80 + q * 20);
#pragma unroll
    for (int i = 0; i < 5; i++) {
      float4 f = p[i];
      a[4*i] = f.x; a[4*i+1] = f.y; a[4*i+2] = f.z; a[4*i+3] = f.w;
    }
  }
#pragma unroll
  for (int i = 0; i < 20; i++) {
    a[i] += __shfl_xor(a[i], 1);
    a[i] += __shfl_xor(a[i], 2);    // (s0+s1)+(s2+s3), same on all 4 lanes
  }

  float uu[20];
  {
    const float4* p = (const float4*)(u + (size_t)g * 20);
#pragma unroll
    for (int i = 0; i < 5; i++) {
      float4 f = p[i];
      uu[4*i] = f.x; uu[4*i+1] = f.y; uu[4*i+2] = f.z; uu[4*i+3] = f.w;
    }
  }

  // h1 slice: j = q*5+o ; h1_j = qb1[j] + a.W1[:,j](rows 0..19) + uu.W1[:,j](rows 20..39)
  float h1[5];
#pragma unroll
  for (int o = 0; o < 5; o++) {
    int j = q * 5 + o;
    const v2f* w = (const v2f*)(sW1T + j * 40);
    v2f acc = {0.0f, 0.0f};
#pragma unroll
    for (int kk = 0; kk < 10; kk++) acc += (v2f){a[2*kk], a[2*kk+1]} * w[kk];
#pragma unroll
    for (int kk = 0; kk < 10; kk++) acc += (v2f){uu[2*kk], uu[2*kk+1]} * w[10 + kk];
    h1[o] = sB[j] + acc.x + acc.y;
  }

  // gather relu(h1) across the 4-lane group (static unroll -> static reg idx)
  float r1[20];
#pragma unroll
  for (int k = 0; k < 20; k++)
    r1[k] = fmaxf(__shfl(h1[k % 5], gl + (k / 5)), 0.0f);

  float h2[5];
#pragma unroll
  for (int o = 0; o < 5; o++) {
    int j = q * 5 + o;
    const v2f* w = (const v2f*)(sW2T + j * 20);
    v2f acc = {0.0f, 0.0f};
#pragma unroll
    for (int kk = 0; kk < 10; kk++) acc += (v2f){r1[2*kk], r1[2*kk+1]} * w[kk];
    h2[o] = sB[20 + j] + acc.x + acc.y;
  }

  float r2[20];
#pragma unroll
  for (int k = 0; k < 20; k++)
    r2[k] = fmaxf(__shfl(h2[k % 5], gl + (k / 5)), 0.0f);

  float h3[5];
#pragma unroll
  for (int o = 0; o < 5; o++) {
    int j = q * 5 + o;
    const v2f* w = (const v2f*)(sW3T + j * 20);
    v2f acc = {0.0f, 0.0f};
#pragma unroll
    for (int kk = 0; kk < 10; kk++) acc += (v2f){r2[2*kk], r2[2*kk+1]} * w[kk];
    h3[o] = sB[40 + j] + acc.x + acc.y;
  }

  // group LayerNorm (fixed-tree butterflies)
  float s = h3[0] + h3[1] + h3[2] + h3[3] + h3[4];
  s += __shfl_xor(s, 1);
  s += __shfl_xor(s, 2);
  float mu = s * 0.05f;
  float d = 0.0f;
#pragma unroll
  for (int o = 0; o < 5; o++) { float dd = h3[o] - mu; d += dd * dd; }
  d += __shfl_xor(d, 1);
  d += __shfl_xor(d, 2);
  float rs = rsqrtf(d * 0.05f + LN_EPS);

  float un[5];
#pragma unroll
  for (int o = 0; o < 5; o++) {
    int j = q * 5 + o;
    un[o] = (h3[o] - mu) * rs * sB[60 + j] + sB[80 + j] + uu[j];  // +residual
  }
#pragma unroll
  for (int o = 0; o < 5; o++) u[(size_t)g * 20 + q * 5 + o] = un[o];

  if (has_next) {
    float ru[20];
#pragma unroll
    for (int k = 0; k < 20; k++)
      ru[k] = __shfl(un[k % 5], gl + (k / 5));
    float gn[5], gg[5];
#pragma unroll
    for (int o = 0; o < 5; o++) {
      int j = q * 5 + o;
      const v2f* wn = (const v2f*)(sNT + j * 20);
      const v2f* wg = (const v2f*)(sGT + j * 20);
      v2f an = {0.0f, 0.0f}, ag = {0.0f, 0.0f};
#pragma unroll
      for (int kk = 0; kk < 10; kk++) {
        v2f rv = {ru[2*kk], ru[2*kk+1]};
        an += rv * wn[kk];
        ag += rv * wg[kk];
      }
      gn[o] = sB[100 + j] + an.x + an.y;
      gg[o] = sB[120 + j] + ag.x + ag.y;
    }
#pragma unroll
    for (int o = 0; o < 5; o++) {
      gu[(size_t)g * 40 + q * 5 + o]      = gn[o];
      gu[(size_t)g * 40 + 20 + q * 5 + o] = gg[o];
    }
  }
}

// ---------------- host launcher ----------------

extern "C" void kernel_launch(void* const* d_in, const int* in_sizes, int n_in,
                              void* d_out, int out_size, void* d_ws, size_t ws_size,
                              hipStream_t stream) {
  const float* x_in  = (const float*)d_in[0];
  const int*   batch = (const int*)  d_in[1];
  const float* ni_W1 = (const float*)d_in[2];
  const float* ni_b1 = (const float*)d_in[3];
  const float* ni_W2 = (const float*)d_in[4];
  const float* ni_b2 = (const float*)d_in[5];
  const float* ni_W3 = (const float*)d_in[6];
  const float* ni_b3 = (const float*)d_in[7];
  const float* ni_g  = (const float*)d_in[8];
  const float* ni_be = (const float*)d_in[9];
  const float* nm_W1 = (const float*)d_in[10];
  const float* nm_b1 = (const float*)d_in[11];
  const float* nm_W2 = (const float*)d_in[12];
  const float* nm_b2 = (const float*)d_in[13];
  const float* nm_W3 = (const float*)d_in[14];
  const float* nm_b3 = (const float*)d_in[15];
  const float* nm_g  = (const float*)d_in[16];
  const float* nm_be = (const float*)d_in[17];
  const float* gp_W1 = (const float*)d_in[18];
  const float* gp_b1 = (const float*)d_in[19];
  const float* gp_W2 = (const float*)d_in[20];
  const float* gp_b2 = (const float*)d_in[21];
  const float* gp_W3 = (const float*)d_in[22];
  const float* gp_b3 = (const float*)d_in[23];
  const float* gp_g  = (const float*)d_in[24];
  const float* gp_be = (const float*)d_in[25];
  const float* gq_W1 = (const float*)d_in[26];
  const float* gq_b1 = (const float*)d_in[27];
  const float* gq_W2 = (const float*)d_in[28];
  const float* gq_b2 = (const float*)d_in[29];
  const float* gq_W3 = (const float*)d_in[30];
  const float* gq_b3 = (const float*)d_in[31];
  const float* gq_g  = (const float*)d_in[32];
  const float* gq_be = (const float*)d_in[33];

  const int N = in_sizes[0] / 10;          // 500000
  float* xs = (float*)d_out;               // x state in d_out[0 .. N*20)
  float* u  = xs + (size_t)N * 20;         // u in d_out tail (NG*20)

  float* part  = (float*)d_ws;             // NG*80 (4 slots x 20 per graph)
  float* gu    = part + NG * 80;           // NG*40 (merged nm|gp table)
  float* wpack = gu + NG * 40;             // L*2560 packed k_node weights

  const int L = 20;
  const int nblk = (N + 255) / 256;
  const int ngrid = nblk < 1792 ? nblk : 1792;   // 7 blocks/CU x 256 CUs

  k_prelayer<<<(NG * 80) / 256, 256, 0, stream>>>(u, part, gu, nm_b1, gp_b1);
  k_pack<<<(L * 2560 + 255) / 256, 256, 0, stream>>>(wpack,
      nm_W1, nm_W2, nm_W3, nm_b2, nm_b3, nm_g, nm_be,
      gp_W1, gp_W2, gp_W3, gp_b2, gp_b3, gp_g, gp_be);
  k_init<<<nblk, 256, 0, stream>>>(x_in, xs, ni_W1, ni_b1, ni_W2, ni_b2,
                                   ni_W3, ni_b3, ni_g, ni_be, N);
  for (int l = 0; l < L; l++) {
    k_node<<<ngrid, 256, 0, stream>>>(batch, xs, (float*)d_ws,
                                      wpack + (size_t)l * 2560, N);
    int has_next = (l < L - 1);
    k_global<<<(NG * 4) / 128, 128, 0, stream>>>(u, part, gu,
        gq_W1 + (size_t)l * 800, gq_b1 + l * 20,
        gq_W2 + (size_t)l * 400, gq_b2 + l * 20,
        gq_W3 + (size_t)l * 400, gq_b3 + l * 20,
        gq_g + l * 20, gq_be + l * 20,
        nm_W1 + (size_t)(l + 1) * 800 + 400, nm_b1 + (l + 1) * 20,
        gp_W1 + (size_t)(l + 1) * 800 + 400, gp_b1 + (l + 1) * 20,
        has_next);
  }
}

// Round 10
// 2265.921 us; speedup vs baseline: 1.7223x; 1.7223x over previous
//
#include <hip/hip_runtime.h>

#define NG 8192
#define LN_EPS 1e-5f

typedef float v2f __attribute__((ext_vector_type(2)));

// ---------------- DPP wave-scan helpers (VALU-only, no LDS pipe) ----------------

__device__ __forceinline__ float wscan_add(float x) {
  x += __int_as_float(__builtin_amdgcn_update_dpp(0, __float_as_int(x), 0x111, 0xF, 0xF, true));
  x += __int_as_float(__builtin_amdgcn_update_dpp(0, __float_as_int(x), 0x112, 0xF, 0xF, true));
  x += __int_as_float(__builtin_amdgcn_update_dpp(0, __float_as_int(x), 0x114, 0xF, 0xF, true));
  x += __int_as_float(__builtin_amdgcn_update_dpp(0, __float_as_int(x), 0x118, 0xF, 0xF, true));
  x += __int_as_float(__builtin_amdgcn_update_dpp(0, __float_as_int(x), 0x142, 0xA, 0xF, false));
  x += __int_as_float(__builtin_amdgcn_update_dpp(0, __float_as_int(x), 0x143, 0xC, 0xF, false));
  return x;
}

__device__ __forceinline__ int wscan_max(int x) {
  int t;
  t = __builtin_amdgcn_update_dpp(0, x, 0x111, 0xF, 0xF, true); x = max(x, t);
  t = __builtin_amdgcn_update_dpp(0, x, 0x112, 0xF, 0xF, true); x = max(x, t);
  t = __builtin_amdgcn_update_dpp(0, x, 0x114, 0xF, 0xF, true); x = max(x, t);
  t = __builtin_amdgcn_update_dpp(0, x, 0x118, 0xF, 0xF, true); x = max(x, t);
  t = __builtin_amdgcn_update_dpp(0, x, 0x142, 0xA, 0xF, false); x = max(x, t);
  t = __builtin_amdgcn_update_dpp(0, x, 0x143, 0xC, 0xF, false); x = max(x, t);
  return x;
}

// ---------------- misc helpers ----------------

__device__ __forceinline__ void stage4(float* dst, const float* __restrict__ src,
                                       int n4, int tid, int nt) {
  float4* d = (float4*)dst;
  const float4* s = (const float4*)src;
  for (int t = tid; t < n4; t += nt) d[t] = s[t];
}

__device__ __forceinline__ void load20v(const float* __restrict__ p, v2f v[10]) {
  const float4* q = (const float4*)p;
#pragma unroll
  for (int t = 0; t < 5; t++) {
    float4 f = q[t];
    v[2*t]   = (v2f){f.x, f.y};
    v[2*t+1] = (v2f){f.z, f.w};
  }
}

__device__ __forceinline__ void store20v(float* __restrict__ p, const v2f v[10]) {
  float4* q = (float4*)p;
#pragma unroll
  for (int t = 0; t < 5; t++)
    q[t] = make_float4(v[2*t].x, v[2*t].y, v[2*t+1].x, v[2*t+1].y);
}

__device__ __forceinline__ float elem(const v2f* a, int k) { return a[k >> 1][k & 1]; }

// LN(relu(relu(h1)@W2+b2)@W3+b3)*g+be — packed fp32 pairs. Works for both
// global (SGPR s_load) and LDS (broadcast ds_read) weight pointers (inlined).
__device__ __forceinline__ void mlp23_ln1(
    const float* __restrict__ W2, const float* __restrict__ b2,
    const float* __restrict__ W3, const float* __restrict__ b3,
    const float* __restrict__ g,  const float* __restrict__ be,
    const v2f h1[10], v2f out[10]) {
  const v2f* W2v = (const v2f*)W2; const v2f* b2v = (const v2f*)b2;
  const v2f* W3v = (const v2f*)W3; const v2f* b3v = (const v2f*)b3;
  const v2f* gv  = (const v2f*)g;  const v2f* bev = (const v2f*)be;
  v2f h2[10];
#pragma unroll
  for (int j = 0; j < 10; j++) h2[j] = b2v[j];
#pragma unroll
  for (int k = 0; k < 20; k++) {
    float a = fmaxf(elem(h1, k), 0.0f); v2f av = {a, a};
#pragma unroll
    for (int j = 0; j < 10; j++) h2[j] += av * W2v[k*10 + j];
  }
  v2f h3[10];
#pragma unroll
  for (int j = 0; j < 10; j++) h3[j] = b3v[j];
#pragma unroll
  for (int k = 0; k < 20; k++) {
    float a = fmaxf(elem(h2, k), 0.0f); v2f av = {a, a};
#pragma unroll
    for (int j = 0; j < 10; j++) h3[j] += av * W3v[k*10 + j];
  }
  float mu = 0.0f;
#pragma unroll
  for (int j = 0; j < 10; j++) mu += h3[j].x + h3[j].y;
  mu *= 0.05f;
  float var = 0.0f;
#pragma unroll
  for (int j = 0; j < 10; j++) {
    float dx = h3[j].x - mu, dy = h3[j].y - mu;
    var += dx*dx + dy*dy;
  }
  var *= 0.05f;
  float rs = rsqrtf(var + LN_EPS);
  v2f muv = {mu, mu}, rsv = {rs, rs};
#pragma unroll
  for (int j = 0; j < 10; j++) out[j] = (h3[j] - muv) * rsv * gv[j] + bev[j];
}

// Full per-node pipeline for a 64-node segment handled by one wave:
// NodeModel MLP (+residual, xs update), pre-aggr MLP, DPP segmented scan,
// run-end slot stores. i must be segment-aligned per wave (i = seg*64+lane)
// so the scan and slot=(i>>6)&3 mapping stay correct.
__device__ __forceinline__ void node_body(
    int i, bool valid, int n, int lane,
    const int* __restrict__ batch, float* __restrict__ xs,
    const float* __restrict__ gu, float* __restrict__ part,
    const float* __restrict__ wl, const float* __restrict__ sm) {
  int ic = valid ? i : (n - 1);
  int b = batch[ic];

  v2f x[10];
  load20v(xs + (size_t)ic * 20, x);

  // ---- NodeModel: h1 = x@W1x + gu_nm[b]  (gu = u@W1u + b1, prefolded) ----
  v2f h1[10];
  load20v(gu + (size_t)b * 40, h1);
  const v2f* W1v = (const v2f*)wl;
#pragma unroll
  for (int k = 0; k < 20; k++) {
    float a = elem(x, k); v2f av = {a, a};
#pragma unroll
    for (int j = 0; j < 10; j++) h1[j] += av * W1v[k*10 + j];
  }
  v2f xn[10];
  mlp23_ln1(wl + 400, wl + 1200, wl + 800, wl + 1220, wl + 1240, wl + 1260,
            h1, xn);
#pragma unroll
  for (int j = 0; j < 10; j++) xn[j] += x[j];     // residual
  if (valid) store20v(xs + (size_t)ic * 20, xn);

  // ---- pre-aggr MLP on updated x (weights from LDS broadcast) ----
  v2f p1[10];
  load20v(gu + (size_t)b * 40 + 20, p1);
  const v2f* G1v = (const v2f*)sm;
#pragma unroll
  for (int k = 0; k < 20; k++) {
    float a = elem(xn, k); v2f av = {a, a};
#pragma unroll
    for (int j = 0; j < 10; j++) p1[j] += av * G1v[k*10 + j];
  }
  v2f pre[10];
  mlp23_ln1(sm + 400, sm + 1200, sm + 800, sm + 1220, sm + 1240, sm + 1260,
            p1, pre);

  // ---- aggregation: DPP scan + run-end slot stores (batch sorted) ----
  int key = valid ? b : -1;
  if (!valid) {
#pragma unroll
    for (int j = 0; j < 10; j++) pre[j] = (v2f){0.0f, 0.0f};
  }
  int pk = __builtin_amdgcn_update_dpp(-1, key, 0x138, 0xF, 0xF, false);
  int nk = __builtin_amdgcn_update_dpp(-2, key, 0x130, 0xF, 0xF, false);
  bool isstart = (key != pk);
  int st = wscan_max(isstart ? lane : 0);   // start lane of my run

#pragma unroll
  for (int j = 0; j < 10; j++) {
    pre[j].x = wscan_add(pre[j].x);
    pre[j].y = wscan_add(pre[j].y);
  }

  int pl = (st > 0) ? (st - 1) : 0;
  float use = (st > 0) ? 1.0f : 0.0f;
  v2f fl[10];
#pragma unroll
  for (int j = 0; j < 10; j++) {
    float bx = __shfl(pre[j].x, pl);
    float by = __shfl(pre[j].y, pl);
    fl[j].x = pre[j].x - use * bx;
    fl[j].y = pre[j].y - use * by;
  }
  bool runend = valid && (nk != key);       // lane63 gets nk=-2 -> true
  if (runend) {
    int slot = (i >> 6) & 3;                // graphs span <=4 consecutive waves
    float* pp = part + (size_t)b * 80 + slot * 20;
#pragma unroll
    for (int j = 0; j < 10; j++) {
      pp[2*j]     = fl[j].x;
      pp[2*j + 1] = fl[j].y;
    }
  }
}

// ---------------- kernels ----------------

__global__ __launch_bounds__(256) void k_prelayer(
    float* __restrict__ u, float* __restrict__ part, float* __restrict__ gu,
    const float* __restrict__ nmb1, const float* __restrict__ gpb1) {
  int t = blockIdx.x * 256 + threadIdx.x;   // NG*80 threads
  part[t] = 0.0f;
  if (t < NG * 40) {
    int j = t % 40;
    gu[t] = (j < 20) ? nmb1[j] : gpb1[j - 20];
  }
  if (t < NG * 20) u[t] = 0.0f;
}

// One-time weight packer: per layer l, blob of 2560 floats =
// [nmW1x 400][nmW2 400][nmW3 400][nmb2 20][nmb3 20][nmg 20][nmbe 20] (=1280)
// [gpW1x 400][gpW2 400][gpW3 400][gpb2 20][gpb3 20][gpg 20][gpbe 20] (=1280)
__global__ __launch_bounds__(256) void k_pack(
    float* __restrict__ wp,
    const float* __restrict__ nmW1, const float* __restrict__ nmW2,
    const float* __restrict__ nmW3, const float* __restrict__ nmb2,
    const float* __restrict__ nmb3, const float* __restrict__ nmg,
    const float* __restrict__ nmbe,
    const float* __restrict__ gpW1, const float* __restrict__ gpW2,
    const float* __restrict__ gpW3, const float* __restrict__ gpb2,
    const float* __restrict__ gpb3, const float* __restrict__ gpg,
    const float* __restrict__ gpbe) {
  int t = blockIdx.x * 256 + threadIdx.x;
  if (t >= 20 * 2560) return;
  int l = t / 2560, r = t % 2560;
  int half = (r >= 1280) ? 1 : 0;
  int rr = r - half * 1280;
  float v;
  if (rr < 400)       v = (half ? gpW1 : nmW1)[l * 800 + rr];       // x-rows only
  else if (rr < 800)  v = (half ? gpW2 : nmW2)[l * 400 + rr - 400];
  else if (rr < 1200) v = (half ? gpW3 : nmW3)[l * 400 + rr - 800];
  else if (rr < 1220) v = (half ? gpb2 : nmb2)[l * 20 + rr - 1200];
  else if (rr < 1240) v = (half ? gpb3 : nmb3)[l * 20 + rr - 1220];
  else if (rr < 1260) v = (half ? gpg  : nmg )[l * 20 + rr - 1240];
  else                v = (half ? gpbe : nmbe)[l * 20 + rr - 1260];
  wp[t] = v;
}

__global__ __launch_bounds__(256) void k_init(
    const float* __restrict__ xin, float* __restrict__ xs,
    const float* __restrict__ W1, const float* __restrict__ b1,
    const float* __restrict__ W2, const float* __restrict__ b2,
    const float* __restrict__ W3, const float* __restrict__ b3,
    const float* __restrict__ gw, const float* __restrict__ bw, int n) {
  int i = blockIdx.x * 256 + threadIdx.x;
  if (i >= n) return;
  float xi[10];
  const float2* xp = (const float2*)(xin + (size_t)i * 10);
#pragma unroll
  for (int t = 0; t < 5; t++) { float2 f = xp[t]; xi[t*2] = f.x; xi[t*2+1] = f.y; }
  const v2f* W1v = (const v2f*)W1; const v2f* b1v = (const v2f*)b1;
  v2f h1[10];
#pragma unroll
  for (int j = 0; j < 10; j++) h1[j] = b1v[j];
#pragma unroll
  for (int k = 0; k < 10; k++) {
    float a = xi[k]; v2f av = {a, a};
#pragma unroll
    for (int j = 0; j < 10; j++) h1[j] += av * W1v[k*10 + j];
  }
  v2f out[10];
  mlp23_ln1(W2, b2, W3, b3, gw, bw, h1, out);
  store20v(xs + (size_t)i * 20, out);
}

// Per-layer node kernel — grid = 1792 (= measured 7 blocks/CU capacity x 256
// CUs) so ALL blocks are co-resident in one generation. The 645 extra
// 64-node segments (7813 total - 7168 resident waves) are spread at WAVE
// granularity: every 11th wave handles one extra segment, i.e. ~2.5 extra
// waves per CU instead of 162 extra BLOCKS on 162 slots (rounds 0-8: that
// block-granular tail re-ran a full ~25us latency generation — half the
// wall). Straight-line two-call structure, NOT a loop: round 9's grid-stride
// loop caused LICM to hoist the loop-invariant weight stream into VGPRs
// under the SGPR cap (VGPR 36 -> 256, 4x regression). Tripwire: VGPR >= 64
// or WRITE_SIZE > 41 MB means codegen blew up again -> revert to round-8.
// Weight split unchanged: nm weights via s_load (SGPR operands), gp blob in
// LDS (broadcast ds_read). Scan + slot stores are absolute-node-indexed, so
// the segment->wave mapping doesn't affect results (deterministic).
__global__ __launch_bounds__(256) __attribute__((amdgpu_num_sgpr(80)))
void k_node(
    const int* __restrict__ batch, float* __restrict__ xs,
    float* __restrict__ ws, const float* __restrict__ wl, int n) {
  float* part = ws;                         // NG*80
  const float* gu = ws + NG * 80;           // NG*40
  __shared__ float sm[1280];
  int tid = threadIdx.x;
  int lane = tid & 63;
  stage4(sm, wl + 1280, 320, tid, 256);     // whole gp blob, contiguous
  __syncthreads();

  // main pass: contiguous 256-node tile per block
  int i = blockIdx.x * 256 + tid;
  node_body(i, i < n, n, lane, batch, xs, gu, part, wl, sm);

  // wave-granular tail: segments [mainS, S) spread one per every-stride'th wave
  int S = (n + 63) >> 6;                    // total 64-node segments
  int mainS = (int)(gridDim.x << 2);        // segments covered by main pass
  int extra = S - mainS;                    // 645 at N=500000, grid=1792
  if (extra > 0) {
    int stride = mainS / extra;             // 11
    int W = (int)(blockIdx.x << 2) + (tid >> 6);
    if (W % stride == 0) {                  // wave-uniform guard
      int k = W / stride;
      if (k < extra) {
        int i2 = ((mainS + k) << 6) + lane;
        node_body(i2, i2 < n, n, lane, batch, xs, gu, part, wl, sm);
      }
    }
  }
}

// Per-layer global kernel, 4 LANES PER GRAPH (NG*4 threads): coalesced slot
// loads, fixed-tree shfl butterflies, transposed weights in LDS. No slot
// re-zero needed — batch is constant across layers, so exactly the same
// (graph, slot) pairs are rewritten every layer; slots never written stay
// at their k_prelayer zeros.
__global__ __launch_bounds__(128) void k_global(
    float* __restrict__ u, float* __restrict__ part, float* __restrict__ gu,
    const float* __restrict__ qW1, const float* __restrict__ qb1,
    const float* __restrict__ qW2, const float* __restrict__ qb2,
    const float* __restrict__ qW3, const float* __restrict__ qb3,
    const float* __restrict__ qg,  const float* __restrict__ qbe,
    const float* __restrict__ nmW1u, const float* __restrict__ nmb1n,
    const float* __restrict__ gpW1u, const float* __restrict__ gpb1n,
    int has_next) {
  __shared__ float sW1T[20 * 40];   // [j][k], k over (agg | u)
  __shared__ float sW2T[20 * 20];   // [j][k]
  __shared__ float sW3T[20 * 20];
  __shared__ float sNT[20 * 20];    // nmW1u^T (next layer)
  __shared__ float sGT[20 * 20];    // gpW1u^T (next layer)
  __shared__ float sB[140];         // qb1|qb2|qb3|qg|qbe|nmb1n|gpb1n
  int tid = threadIdx.x;
  for (int e = tid; e < 800; e += 128) sW1T[(e % 20) * 40 + (e / 20)] = qW1[e];
  for (int e = tid; e < 400; e += 128) {
    int k = e / 20, j = e % 20;
    sW2T[j * 20 + k] = qW2[e];
    sW3T[j * 20 + k] = qW3[e];
    sNT[j * 20 + k]  = nmW1u[e];
    sGT[j * 20 + k]  = gpW1u[e];
  }
  if (tid < 20) {
    sB[tid]       = qb1[tid];
    sB[20 + tid]  = qb2[tid];
    sB[40 + tid]  = qb3[tid];
    sB[60 + tid]  = qg[tid];
    sB[80 + tid]  = qbe[tid];
    sB[100 + tid] = nmb1n[tid];
    sB[120 + tid] = gpb1n[tid];
  }
  __syncthreads();

  int t = blockIdx.x * 128 + tid;   // exactly NG*4 threads
  int g = t >> 2;                   // graph
  int q = t & 3;                    // quarter: output cols [q*5, q*5+5)
  int lane = tid & 63;
  int gl = lane & ~3;               // group base lane (groups never cross waves)

  // my partial slot (coalesced 80B/lane), then fixed-tree butterfly sum
  float a[20];
  {
    const float4* p = (const float4*)(part + (size_t)g * 80 + q * 20);
#pragma unroll
    for (int i = 0; i < 5; i++) {
      float4 f = p[i];
      a[4*i] = f.x; a[4*i+1] = f.y; a[4*i+2] = f.z; a[4*i+3] = f.w;
    }
  }
#pragma unroll
  for (int i = 0; i < 20; i++) {
    a[i] += __shfl_xor(a[i], 1);
    a[i] += __shfl_xor(a[i], 2);    // (s0+s1)+(s2+s3), same on all 4 lanes
  }

  float uu[20];
  {
    const float4* p = (const float4*)(u + (size_t)g * 20);
#pragma unroll
    for (int i = 0; i < 5; i++) {
      float4 f = p[i];
      uu[4*i] = f.x; uu[4*i+1] = f.y; uu[4*i+2] = f.z; uu[4*i+3] = f.w;
    }
  }

  // h1 slice: j = q*5+o ; h1_j = qb1[j] + a.W1[:,j](rows 0..19) + uu.W1[:,j](rows 20..39)
  float h1[5];
#pragma unroll
  for (int o = 0; o < 5; o++) {
    int j = q * 5 + o;
    const v2f* w = (const v2f*)(sW1T + j * 40);
    v2f acc = {0.0f, 0.0f};
#pragma unroll
    for (int kk = 0; kk < 10; kk++) acc += (v2f){a[2*kk], a[2*kk+1]} * w[kk];
#pragma unroll
    for (int kk = 0; kk < 10; kk++) acc += (v2f){uu[2*kk], uu[2*kk+1]} * w[10 + kk];
    h1[o] = sB[j] + acc.x + acc.y;
  }

  // gather relu(h1) across the 4-lane group (static unroll -> static reg idx)
  float r1[20];
#pragma unroll
  for (int k = 0; k < 20; k++)
    r1[k] = fmaxf(__shfl(h1[k % 5], gl + (k / 5)), 0.0f);

  float h2[5];
#pragma unroll
  for (int o = 0; o < 5; o++) {
    int j = q * 5 + o;
    const v2f* w = (const v2f*)(sW2T + j * 20);
    v2f acc = {0.0f, 0.0f};
#pragma unroll
    for (int kk = 0; kk < 10; kk++) acc += (v2f){r1[2*kk], r1[2*kk+1]} * w[kk];
    h2[o] = sB[20 + j] + acc.x + acc.y;
  }

  float r2[20];
#pragma unroll
  for (int k = 0; k < 20; k++)
    r2[k] = fmaxf(__shfl(h2[k % 5], gl + (k / 5)), 0.0f);

  float h3[5];
#pragma unroll
  for (int o = 0; o < 5; o++) {
    int j = q * 5 + o;
    const v2f* w = (const v2f*)(sW3T + j * 20);
    v2f acc = {0.0f, 0.0f};
#pragma unroll
    for (int kk = 0; kk < 10; kk++) acc += (v2f){r2[2*kk], r2[2*kk+1]} * w[kk];
    h3[o] = sB[40 + j] + acc.x + acc.y;
  }

  // group LayerNorm (fixed-tree butterflies)
  float s = h3[0] + h3[1] + h3[2] + h3[3] + h3[4];
  s += __shfl_xor(s, 1);
  s += __shfl_xor(s, 2);
  float mu = s * 0.05f;
  float d = 0.0f;
#pragma unroll
  for (int o = 0; o < 5; o++) { float dd = h3[o] - mu; d += dd * dd; }
  d += __shfl_xor(d, 1);
  d += __shfl_xor(d, 2);
  float rs = rsqrtf(d * 0.05f + LN_EPS);

  float un[5];
#pragma unroll
  for (int o = 0; o < 5; o++) {
    int j = q * 5 + o;
    un[o] = (h3[o] - mu) * rs * sB[60 + j] + sB[80 + j] + uu[j];  // +residual
  }
#pragma unroll
  for (int o = 0; o < 5; o++) u[(size_t)g * 20 + q * 5 + o] = un[o];

  if (has_next) {
    float ru[20];
#pragma unroll
    for (int k = 0; k < 20; k++)
      ru[k] = __shfl(un[k % 5], gl + (k / 5));
    float gn[5], gg[5];
#pragma unroll
    for (int o = 0; o < 5; o++) {
      int j = q * 5 + o;
      const v2f* wn = (const v2f*)(sNT + j * 20);
      const v2f* wg = (const v2f*)(sGT + j * 20);
      v2f an = {0.0f, 0.0f}, ag = {0.0f, 0.0f};
#pragma unroll
      for (int kk = 0; kk < 10; kk++) {
        v2f rv = {ru[2*kk], ru[2*kk+1]};
        an += rv * wn[kk];
        ag += rv * wg[kk];
      }
      gn[o] = sB[100 + j] + an.x + an.y;
      gg[o] = sB[120 + j] + ag.x + ag.y;
    }
#pragma unroll
    for (int o = 0; o < 5; o++) {
      gu[(size_t)g * 40 + q * 5 + o]      = gn[o];
      gu[(size_t)g * 40 + 20 + q * 5 + o] = gg[o];
    }
  }
}

// ---------------- host launcher ----------------

extern "C" void kernel_launch(void* const* d_in, const int* in_sizes, int n_in,
                              void* d_out, int out_size, void* d_ws, size_t ws_size,
                              hipStream_t stream) {
  const float* x_in  = (const float*)d_in[0];
  const int*   batch = (const int*)  d_in[1];
  const float* ni_W1 = (const float*)d_in[2];
  const float* ni_b1 = (const float*)d_in[3];
  const float* ni_W2 = (const float*)d_in[4];
  const float* ni_b2 = (const float*)d_in[5];
  const float* ni_W3 = (const float*)d_in[6];
  const float* ni_b3 = (const float*)d_in[7];
  const float* ni_g  = (const float*)d_in[8];
  const float* ni_be = (const float*)d_in[9];
  const float* nm_W1 = (const float*)d_in[10];
  const float* nm_b1 = (const float*)d_in[11];
  const float* nm_W2 = (const float*)d_in[12];
  const float* nm_b2 = (const float*)d_in[13];
  const float* nm_W3 = (const float*)d_in[14];
  const float* nm_b3 = (const float*)d_in[15];
  const float* nm_g  = (const float*)d_in[16];
  const float* nm_be = (const float*)d_in[17];
  const float* gp_W1 = (const float*)d_in[18];
  const float* gp_b1 = (const float*)d_in[19];
  const float* gp_W2 = (const float*)d_in[20];
  const float* gp_b2 = (const float*)d_in[21];
  const float* gp_W3 = (const float*)d_in[22];
  const float* gp_b3 = (const float*)d_in[23];
  const float* gp_g  = (const float*)d_in[24];
  const float* gp_be = (const float*)d_in[25];
  const float* gq_W1 = (const float*)d_in[26];
  const float* gq_b1 = (const float*)d_in[27];
  const float* gq_W2 = (const float*)d_in[28];
  const float* gq_b2 = (const float*)d_in[29];
  const float* gq_W3 = (const float*)d_in[30];
  const float* gq_b3 = (const float*)d_in[31];
  const float* gq_g  = (const float*)d_in[32];
  const float* gq_be = (const float*)d_in[33];

  const int N = in_sizes[0] / 10;          // 500000
  float* xs = (float*)d_out;               // x state in d_out[0 .. N*20)
  float* u  = xs + (size_t)N * 20;         // u in d_out tail (NG*20)

  float* part  = (float*)d_ws;             // NG*80 (4 slots x 20 per graph)
  float* gu    = part + NG * 80;           // NG*40 (merged nm|gp table)
  float* wpack = gu + NG * 40;             // L*2560 packed k_node weights

  const int L = 20;
  const int nblk = (N + 255) / 256;
  const int ngrid = nblk < 1792 ? nblk : 1792;   // 7 blocks/CU x 256 CUs

  k_prelayer<<<(NG * 80) / 256, 256, 0, stream>>>(u, part, gu, nm_b1, gp_b1);
  k_pack<<<(L * 2560 + 255) / 256, 256, 0, stream>>>(wpack,
      nm_W1, nm_W2, nm_W3, nm_b2, nm_b3, nm_g, nm_be,
      gp_W1, gp_W2, gp_W3, gp_b2, gp_b3, gp_g, gp_be);
  k_init<<<nblk, 256, 0, stream>>>(x_in, xs, ni_W1, ni_b1, ni_W2, ni_b2,
                                   ni_W3, ni_b3, ni_g, ni_be, N);
  for (int l = 0; l < L; l++) {
    k_node<<<ngrid, 256, 0, stream>>>(batch, xs, (float*)d_ws,
                                      wpack + (size_t)l * 2560, N);
    int has_next = (l < L - 1);
    k_global<<<(NG * 4) / 128, 128, 0, stream>>>(u, part, gu,
        gq_W1 + (size_t)l * 800, gq_b1 + l * 20,
        gq_W2 + (size_t)l * 400, gq_b2 + l * 20,
        gq_W3 + (size_t)l * 400, gq_b3 + l * 20,
        gq_g + l * 20, gq_be + l * 20,
        nm_W1 + (size_t)(l + 1) * 800 + 400, nm_b1 + (l + 1) * 20,
        gp_W1 + (size_t)(l + 1) * 800 + 400, gp_b1 + (l + 1) * 20,
        has_next);
  }
}

// Round 11
// 1747.655 us; speedup vs baseline: 2.2331x; 1.2965x over previous
//
#include <hip/hip_runtime.h>

#define NG 8192
#define LN_EPS 1e-5f

typedef float v2f __attribute__((ext_vector_type(2)));

// ---------------- DPP wave-scan helpers (VALU-only, no LDS pipe) ----------------

__device__ __forceinline__ float wscan_add(float x) {
  x += __int_as_float(__builtin_amdgcn_update_dpp(0, __float_as_int(x), 0x111, 0xF, 0xF, true));
  x += __int_as_float(__builtin_amdgcn_update_dpp(0, __float_as_int(x), 0x112, 0xF, 0xF, true));
  x += __int_as_float(__builtin_amdgcn_update_dpp(0, __float_as_int(x), 0x114, 0xF, 0xF, true));
  x += __int_as_float(__builtin_amdgcn_update_dpp(0, __float_as_int(x), 0x118, 0xF, 0xF, true));
  x += __int_as_float(__builtin_amdgcn_update_dpp(0, __float_as_int(x), 0x142, 0xA, 0xF, false));
  x += __int_as_float(__builtin_amdgcn_update_dpp(0, __float_as_int(x), 0x143, 0xC, 0xF, false));
  return x;
}

__device__ __forceinline__ int wscan_max(int x) {
  int t;
  t = __builtin_amdgcn_update_dpp(0, x, 0x111, 0xF, 0xF, true); x = max(x, t);
  t = __builtin_amdgcn_update_dpp(0, x, 0x112, 0xF, 0xF, true); x = max(x, t);
  t = __builtin_amdgcn_update_dpp(0, x, 0x114, 0xF, 0xF, true); x = max(x, t);
  t = __builtin_amdgcn_update_dpp(0, x, 0x118, 0xF, 0xF, true); x = max(x, t);
  t = __builtin_amdgcn_update_dpp(0, x, 0x142, 0xA, 0xF, false); x = max(x, t);
  t = __builtin_amdgcn_update_dpp(0, x, 0x143, 0xC, 0xF, false); x = max(x, t);
  return x;
}

// ---------------- misc helpers ----------------

__device__ __forceinline__ void stage4(float* dst, const float* __restrict__ src,
                                       int n4, int tid, int nt) {
  float4* d = (float4*)dst;
  const float4* s = (const float4*)src;
  for (int t = tid; t < n4; t += nt) d[t] = s[t];
}

__device__ __forceinline__ void load20v(const float* __restrict__ p, v2f v[10]) {
  const float4* q = (const float4*)p;
#pragma unroll
  for (int t = 0; t < 5; t++) {
    float4 f = q[t];
    v[2*t]   = (v2f){f.x, f.y};
    v[2*t+1] = (v2f){f.z, f.w};
  }
}

__device__ __forceinline__ void store20v(float* __restrict__ p, const v2f v[10]) {
  float4* q = (float4*)p;
#pragma unroll
  for (int t = 0; t < 5; t++)
    q[t] = make_float4(v[2*t].x, v[2*t].y, v[2*t+1].x, v[2*t+1].y);
}

__device__ __forceinline__ float elem(const v2f* a, int k) { return a[k >> 1][k & 1]; }

// LN(relu(relu(h1)@W2+b2)@W3+b3)*g+be — packed fp32 pairs. Works for both
// global (SGPR s_load) and LDS (broadcast ds_read) weight pointers (inlined).
__device__ __forceinline__ void mlp23_ln1(
    const float* __restrict__ W2, const float* __restrict__ b2,
    const float* __restrict__ W3, const float* __restrict__ b3,
    const float* __restrict__ g,  const float* __restrict__ be,
    const v2f h1[10], v2f out[10]) {
  const v2f* W2v = (const v2f*)W2; const v2f* b2v = (const v2f*)b2;
  const v2f* W3v = (const v2f*)W3; const v2f* b3v = (const v2f*)b3;
  const v2f* gv  = (const v2f*)g;  const v2f* bev = (const v2f*)be;
  v2f h2[10];
#pragma unroll
  for (int j = 0; j < 10; j++) h2[j] = b2v[j];
#pragma unroll
  for (int k = 0; k < 20; k++) {
    float a = fmaxf(elem(h1, k), 0.0f); v2f av = {a, a};
#pragma unroll
    for (int j = 0; j < 10; j++) h2[j] += av * W2v[k*10 + j];
  }
  v2f h3[10];
#pragma unroll
  for (int j = 0; j < 10; j++) h3[j] = b3v[j];
#pragma unroll
  for (int k = 0; k < 20; k++) {
    float a = fmaxf(elem(h2, k), 0.0f); v2f av = {a, a};
#pragma unroll
    for (int j = 0; j < 10; j++) h3[j] += av * W3v[k*10 + j];
  }
  float mu = 0.0f;
#pragma unroll
  for (int j = 0; j < 10; j++) mu += h3[j].x + h3[j].y;
  mu *= 0.05f;
  float var = 0.0f;
#pragma unroll
  for (int j = 0; j < 10; j++) {
    float dx = h3[j].x - mu, dy = h3[j].y - mu;
    var += dx*dx + dy*dy;
  }
  var *= 0.05f;
  float rs = rsqrtf(var + LN_EPS);
  v2f muv = {mu, mu}, rsv = {rs, rs};
#pragma unroll
  for (int j = 0; j < 10; j++) out[j] = (h3[j] - muv) * rsv * gv[j] + bev[j];
}

// Full per-node pipeline for a 64-node segment handled by one wave:
// NodeModel MLP (+residual, xs update), pre-aggr MLP, DPP segmented scan,
// run-end slot stores. i must be segment-aligned per wave (i = seg*64+lane)
// so the scan and slot=(i>>6)&3 mapping stay correct.
__device__ __forceinline__ void node_body(
    int i, bool valid, int n, int lane,
    const int* __restrict__ batch, float* __restrict__ xs,
    const float* __restrict__ gu, float* __restrict__ part,
    const float* __restrict__ wl, const float* __restrict__ sm) {
  int ic = valid ? i : (n - 1);
  int b = batch[ic];

  v2f x[10];
  load20v(xs + (size_t)ic * 20, x);

  // ---- NodeModel: h1 = x@W1x + gu_nm[b]  (gu = u@W1u + b1, prefolded) ----
  v2f h1[10];
  load20v(gu + (size_t)b * 40, h1);
  const v2f* W1v = (const v2f*)wl;
#pragma unroll
  for (int k = 0; k < 20; k++) {
    float a = elem(x, k); v2f av = {a, a};
#pragma unroll
    for (int j = 0; j < 10; j++) h1[j] += av * W1v[k*10 + j];
  }
  v2f xn[10];
  mlp23_ln1(wl + 400, wl + 1200, wl + 800, wl + 1220, wl + 1240, wl + 1260,
            h1, xn);
#pragma unroll
  for (int j = 0; j < 10; j++) xn[j] += x[j];     // residual
  if (valid) store20v(xs + (size_t)ic * 20, xn);

  // ---- pre-aggr MLP on updated x (weights from LDS broadcast) ----
  v2f p1[10];
  load20v(gu + (size_t)b * 40 + 20, p1);
  const v2f* G1v = (const v2f*)sm;
#pragma unroll
  for (int k = 0; k < 20; k++) {
    float a = elem(xn, k); v2f av = {a, a};
#pragma unroll
    for (int j = 0; j < 10; j++) p1[j] += av * G1v[k*10 + j];
  }
  v2f pre[10];
  mlp23_ln1(sm + 400, sm + 1200, sm + 800, sm + 1220, sm + 1240, sm + 1260,
            p1, pre);

  // ---- aggregation: DPP scan + run-end slot stores (batch sorted) ----
  int key = valid ? b : -1;
  if (!valid) {
#pragma unroll
    for (int j = 0; j < 10; j++) pre[j] = (v2f){0.0f, 0.0f};
  }
  int pk = __builtin_amdgcn_update_dpp(-1, key, 0x138, 0xF, 0xF, false);
  int nk = __builtin_amdgcn_update_dpp(-2, key, 0x130, 0xF, 0xF, false);
  bool isstart = (key != pk);
  int st = wscan_max(isstart ? lane : 0);   // start lane of my run

#pragma unroll
  for (int j = 0; j < 10; j++) {
    pre[j].x = wscan_add(pre[j].x);
    pre[j].y = wscan_add(pre[j].y);
  }

  int pl = (st > 0) ? (st - 1) : 0;
  float use = (st > 0) ? 1.0f : 0.0f;
  v2f fl[10];
#pragma unroll
  for (int j = 0; j < 10; j++) {
    float bx = __shfl(pre[j].x, pl);
    float by = __shfl(pre[j].y, pl);
    fl[j].x = pre[j].x - use * bx;
    fl[j].y = pre[j].y - use * by;
  }
  bool runend = valid && (nk != key);       // lane63 gets nk=-2 -> true
  if (runend) {
    int slot = (i >> 6) & 3;                // graphs span <=4 consecutive waves
    float* pp = part + (size_t)b * 80 + slot * 20;
#pragma unroll
    for (int j = 0; j < 10; j++) {
      pp[2*j]     = fl[j].x;
      pp[2*j + 1] = fl[j].y;
    }
  }
}

// ---------------- kernels ----------------

__global__ __launch_bounds__(256) void k_prelayer(
    float* __restrict__ u, float* __restrict__ part, float* __restrict__ gu,
    const float* __restrict__ nmb1, const float* __restrict__ gpb1) {
  int t = blockIdx.x * 256 + threadIdx.x;   // NG*80 threads
  part[t] = 0.0f;
  if (t < NG * 40) {
    int j = t % 40;
    gu[t] = (j < 20) ? nmb1[j] : gpb1[j - 20];
  }
  if (t < NG * 20) u[t] = 0.0f;
}

// One-time weight packer: per layer l, blob of 2560 floats =
// [nmW1x 400][nmW2 400][nmW3 400][nmb2 20][nmb3 20][nmg 20][nmbe 20] (=1280)
// [gpW1x 400][gpW2 400][gpW3 400][gpb2 20][gpb3 20][gpg 20][gpbe 20] (=1280)
__global__ __launch_bounds__(256) void k_pack(
    float* __restrict__ wp,
    const float* __restrict__ nmW1, const float* __restrict__ nmW2,
    const float* __restrict__ nmW3, const float* __restrict__ nmb2,
    const float* __restrict__ nmb3, const float* __restrict__ nmg,
    const float* __restrict__ nmbe,
    const float* __restrict__ gpW1, const float* __restrict__ gpW2,
    const float* __restrict__ gpW3, const float* __restrict__ gpb2,
    const float* __restrict__ gpb3, const float* __restrict__ gpg,
    const float* __restrict__ gpbe) {
  int t = blockIdx.x * 256 + threadIdx.x;
  if (t >= 20 * 2560) return;
  int l = t / 2560, r = t % 2560;
  int half = (r >= 1280) ? 1 : 0;
  int rr = r - half * 1280;
  float v;
  if (rr < 400)       v = (half ? gpW1 : nmW1)[l * 800 + rr];       // x-rows only
  else if (rr < 800)  v = (half ? gpW2 : nmW2)[l * 400 + rr - 400];
  else if (rr < 1200) v = (half ? gpW3 : nmW3)[l * 400 + rr - 800];
  else if (rr < 1220) v = (half ? gpb2 : nmb2)[l * 20 + rr - 1200];
  else if (rr < 1240) v = (half ? gpb3 : nmb3)[l * 20 + rr - 1220];
  else if (rr < 1260) v = (half ? gpg  : nmg )[l * 20 + rr - 1240];
  else                v = (half ? gpbe : nmbe)[l * 20 + rr - 1260];
  wp[t] = v;
}

__global__ __launch_bounds__(256) void k_init(
    const float* __restrict__ xin, float* __restrict__ xs,
    const float* __restrict__ W1, const float* __restrict__ b1,
    const float* __restrict__ W2, const float* __restrict__ b2,
    const float* __restrict__ W3, const float* __restrict__ b3,
    const float* __restrict__ gw, const float* __restrict__ bw, int n) {
  int i = blockIdx.x * 256 + threadIdx.x;
  if (i >= n) return;
  float xi[10];
  const float2* xp = (const float2*)(xin + (size_t)i * 10);
#pragma unroll
  for (int t = 0; t < 5; t++) { float2 f = xp[t]; xi[t*2] = f.x; xi[t*2+1] = f.y; }
  const v2f* W1v = (const v2f*)W1; const v2f* b1v = (const v2f*)b1;
  v2f h1[10];
#pragma unroll
  for (int j = 0; j < 10; j++) h1[j] = b1v[j];
#pragma unroll
  for (int k = 0; k < 10; k++) {
    float a = xi[k]; v2f av = {a, a};
#pragma unroll
    for (int j = 0; j < 10; j++) h1[j] += av * W1v[k*10 + j];
  }
  v2f out[10];
  mlp23_ln1(W2, b2, W3, b3, gw, bw, h1, out);
  store20v(xs + (size_t)i * 20, out);
}

// Per-layer node kernel — grid = 1792 (measured single-generation capacity;
// r3's SGPR=64/VGPR=32 run proved the cap is NOT register-driven) so all
// blocks co-reside. The 645 extra 64-node segments are spread at WAVE
// granularity (every 11th wave does a second segment, ~2.5/CU) instead of
// 162 straggler BLOCKS re-running a full ~25us generation (rounds 0-8).
// r10 failed because the scheduler interleaved the two inlined bodies'
// live ranges (VGPR 36->64 -> residency halved). Fix: a single
// sched_barrier(0) fence between the bodies — no tail instruction
// (including speculated loads) may move above it, so live ranges cannot
// overlap and VGPR stays ~single-body. Tripwire: VGPR >= 64 -> revert r8.
// Weight split unchanged: nm via s_load (SGPR), gp blob in LDS (broadcast
// ds_read). Scan + slot stores are absolute-node-indexed -> deterministic.
__global__ __launch_bounds__(256) __attribute__((amdgpu_num_sgpr(80)))
void k_node(
    const int* __restrict__ batch, float* __restrict__ xs,
    float* __restrict__ ws, const float* __restrict__ wl, int n) {
  float* part = ws;                         // NG*80
  const float* gu = ws + NG * 80;           // NG*40
  __shared__ float sm[1280];
  int tid = threadIdx.x;
  int lane = tid & 63;
  stage4(sm, wl + 1280, 320, tid, 256);     // whole gp blob, contiguous
  __syncthreads();

  // main pass: contiguous 256-node tile per block
  int i = blockIdx.x * 256 + tid;
  node_body(i, i < n, n, lane, batch, xs, gu, part, wl, sm);

  // fence: forbid any tail instruction (incl. speculated loads) from being
  // scheduled into the main body -> live ranges stay disjoint (r10 fix)
  __builtin_amdgcn_sched_barrier(0);

  // wave-granular tail: segments [mainS, S) spread one per every-stride'th wave
  int S = (n + 63) >> 6;                    // total 64-node segments
  int mainS = (int)(gridDim.x << 2);        // segments covered by main pass
  int extra = S - mainS;                    // 645 at N=500000, grid=1792
  if (extra > 0) {
    int stride = mainS / extra;             // 11
    int W = (int)(blockIdx.x << 2) + (tid >> 6);
    if (W % stride == 0) {                  // wave-uniform guard
      int k = W / stride;
      if (k < extra) {
        __builtin_amdgcn_sched_barrier(0);
        int i2 = ((mainS + k) << 6) + lane;
        node_body(i2, i2 < n, n, lane, batch, xs, gu, part, wl, sm);
      }
    }
  }
}

// Per-layer global kernel, 4 LANES PER GRAPH (NG*4 threads): coalesced slot
// loads, fixed-tree shfl butterflies, transposed weights in LDS. No slot
// re-zero needed — batch is constant across layers, so exactly the same
// (graph, slot) pairs are rewritten every layer; slots never written stay
// at their k_prelayer zeros.
__global__ __launch_bounds__(128) void k_global(
    float* __restrict__ u, float* __restrict__ part, float* __restrict__ gu,
    const float* __restrict__ qW1, const float* __restrict__ qb1,
    const float* __restrict__ qW2, const float* __restrict__ qb2,
    const float* __restrict__ qW3, const float* __restrict__ qb3,
    const float* __restrict__ qg,  const float* __restrict__ qbe,
    const float* __restrict__ nmW1u, const float* __restrict__ nmb1n,
    const float* __restrict__ gpW1u, const float* __restrict__ gpb1n,
    int has_next) {
  __shared__ float sW1T[20 * 40];   // [j][k], k over (agg | u)
  __shared__ float sW2T[20 * 20];   // [j][k]
  __shared__ float sW3T[20 * 20];
  __shared__ float sNT[20 * 20];    // nmW1u^T (next layer)
  __shared__ float sGT[20 * 20];    // gpW1u^T (next layer)
  __shared__ float sB[140];         // qb1|qb2|qb3|qg|qbe|nmb1n|gpb1n
  int tid = threadIdx.x;
  for (int e = tid; e < 800; e += 128) sW1T[(e % 20) * 40 + (e / 20)] = qW1[e];
  for (int e = tid; e < 400; e += 128) {
    int k = e / 20, j = e % 20;
    sW2T[j * 20 + k] = qW2[e];
    sW3T[j * 20 + k] = qW3[e];
    sNT[j * 20 + k]  = nmW1u[e];
    sGT[j * 20 + k]  = gpW1u[e];
  }
  if (tid < 20) {
    sB[tid]       = qb1[tid];
    sB[20 + tid]  = qb2[tid];
    sB[40 + tid]  = qb3[tid];
    sB[60 + tid]  = qg[tid];
    sB[80 + tid]  = qbe[tid];
    sB[100 + tid] = nmb1n[tid];
    sB[120 + tid] = gpb1n[tid];
  }
  __syncthreads();

  int t = blockIdx.x * 128 + tid;   // exactly NG*4 threads
  int g = t >> 2;                   // graph
  int q = t & 3;                    // quarter: output cols [q*5, q*5+5)
  int lane = tid & 63;
  int gl = lane & ~3;               // group base lane (groups never cross waves)

  // my partial slot (coalesced 80B/lane), then fixed-tree butterfly sum
  float a[20];
  {
    const float4* p = (const float4*)(part + (size_t)g * 80 + q * 20);
#pragma unroll
    for (int i = 0; i < 5; i++) {
      float4 f = p[i];
      a[4*i] = f.x; a[4*i+1] = f.y; a[4*i+2] = f.z; a[4*i+3] = f.w;
    }
  }
#pragma unroll
  for (int i = 0; i < 20; i++) {
    a[i] += __shfl_xor(a[i], 1);
    a[i] += __shfl_xor(a[i], 2);    // (s0+s1)+(s2+s3), same on all 4 lanes
  }

  float uu[20];
  {
    const float4* p = (const float4*)(u + (size_t)g * 20);
#pragma unroll
    for (int i = 0; i < 5; i++) {
      float4 f = p[i];
      uu[4*i] = f.x; uu[4*i+1] = f.y; uu[4*i+2] = f.z; uu[4*i+3] = f.w;
    }
  }

  // h1 slice: j = q*5+o ; h1_j = qb1[j] + a.W1[:,j](rows 0..19) + uu.W1[:,j](rows 20..39)
  float h1[5];
#pragma unroll
  for (int o = 0; o < 5; o++) {
    int j = q * 5 + o;
    const v2f* w = (const v2f*)(sW1T + j * 40);
    v2f acc = {0.0f, 0.0f};
#pragma unroll
    for (int kk = 0; kk < 10; kk++) acc += (v2f){a[2*kk], a[2*kk+1]} * w[kk];
#pragma unroll
    for (int kk = 0; kk < 10; kk++) acc += (v2f){uu[2*kk], uu[2*kk+1]} * w[10 + kk];
    h1[o] = sB[j] + acc.x + acc.y;
  }

  // gather relu(h1) across the 4-lane group (static unroll -> static reg idx)
  float r1[20];
#pragma unroll
  for (int k = 0; k < 20; k++)
    r1[k] = fmaxf(__shfl(h1[k % 5], gl + (k / 5)), 0.0f);

  float h2[5];
#pragma unroll
  for (int o = 0; o < 5; o++) {
    int j = q * 5 + o;
    const v2f* w = (const v2f*)(sW2T + j * 20);
    v2f acc = {0.0f, 0.0f};
#pragma unroll
    for (int kk = 0; kk < 10; kk++) acc += (v2f){r1[2*kk], r1[2*kk+1]} * w[kk];
    h2[o] = sB[20 + j] + acc.x + acc.y;
  }

  float r2[20];
#pragma unroll
  for (int k = 0; k < 20; k++)
    r2[k] = fmaxf(__shfl(h2[k % 5], gl + (k / 5)), 0.0f);

  float h3[5];
#pragma unroll
  for (int o = 0; o < 5; o++) {
    int j = q * 5 + o;
    const v2f* w = (const v2f*)(sW3T + j * 20);
    v2f acc = {0.0f, 0.0f};
#pragma unroll
    for (int kk = 0; kk < 10; kk++) acc += (v2f){r2[2*kk], r2[2*kk+1]} * w[kk];
    h3[o] = sB[40 + j] + acc.x + acc.y;
  }

  // group LayerNorm (fixed-tree butterflies)
  float s = h3[0] + h3[1] + h3[2] + h3[3] + h3[4];
  s += __shfl_xor(s, 1);
  s += __shfl_xor(s, 2);
  float mu = s * 0.05f;
  float d = 0.0f;
#pragma unroll
  for (int o = 0; o < 5; o++) { float dd = h3[o] - mu; d += dd * dd; }
  d += __shfl_xor(d, 1);
  d += __shfl_xor(d, 2);
  float rs = rsqrtf(d * 0.05f + LN_EPS);

  float un[5];
#pragma unroll
  for (int o = 0; o < 5; o++) {
    int j = q * 5 + o;
    un[o] = (h3[o] - mu) * rs * sB[60 + j] + sB[80 + j] + uu[j];  // +residual
  }
#pragma unroll
  for (int o = 0; o < 5; o++) u[(size_t)g * 20 + q * 5 + o] = un[o];

  if (has_next) {
    float ru[20];
#pragma unroll
    for (int k = 0; k < 20; k++)
      ru[k] = __shfl(un[k % 5], gl + (k / 5));
    float gn[5], gg[5];
#pragma unroll
    for (int o = 0; o < 5; o++) {
      int j = q * 5 + o;
      const v2f* wn = (const v2f*)(sNT + j * 20);
      const v2f* wg = (const v2f*)(sGT + j * 20);
      v2f an = {0.0f, 0.0f}, ag = {0.0f, 0.0f};
#pragma unroll
      for (int kk = 0; kk < 10; kk++) {
        v2f rv = {ru[2*kk], ru[2*kk+1]};
        an += rv * wn[kk];
        ag += rv * wg[kk];
      }
      gn[o] = sB[100 + j] + an.x + an.y;
      gg[o] = sB[120 + j] + ag.x + ag.y;
    }
#pragma unroll
    for (int o = 0; o < 5; o++) {
      gu[(size_t)g * 40 + q * 5 + o]      = gn[o];
      gu[(size_t)g * 40 + 20 + q * 5 + o] = gg[o];
    }
  }
}

// ---------------- host launcher ----------------

extern "C" void kernel_launch(void* const* d_in, const int* in_sizes, int n_in,
                              void* d_out, int out_size, void* d_ws, size_t ws_size,
                              hipStream_t stream) {
  const float* x_in  = (const float*)d_in[0];
  const int*   batch = (const int*)  d_in[1];
  const float* ni_W1 = (const float*)d_in[2];
  const float* ni_b1 = (const float*)d_in[3];
  const float* ni_W2 = (const float*)d_in[4];
  const float* ni_b2 = (const float*)d_in[5];
  const float* ni_W3 = (const float*)d_in[6];
  const float* ni_b3 = (const float*)d_in[7];
  const float* ni_g  = (const float*)d_in[8];
  const float* ni_be = (const float*)d_in[9];
  const float* nm_W1 = (const float*)d_in[10];
  const float* nm_b1 = (const float*)d_in[11];
  const float* nm_W2 = (const float*)d_in[12];
  const float* nm_b2 = (const float*)d_in[13];
  const float* nm_W3 = (const float*)d_in[14];
  const float* nm_b3 = (const float*)d_in[15];
  const float* nm_g  = (const float*)d_in[16];
  const float* nm_be = (const float*)d_in[17];
  const float* gp_W1 = (const float*)d_in[18];
  const float* gp_b1 = (const float*)d_in[19];
  const float* gp_W2 = (const float*)d_in[20];
  const float* gp_b2 = (const float*)d_in[21];
  const float* gp_W3 = (const float*)d_in[22];
  const float* gp_b3 = (const float*)d_in[23];
  const float* gp_g  = (const float*)d_in[24];
  const float* gp_be = (const float*)d_in[25];
  const float* gq_W1 = (const float*)d_in[26];
  const float* gq_b1 = (const float*)d_in[27];
  const float* gq_W2 = (const float*)d_in[28];
  const float* gq_b2 = (const float*)d_in[29];
  const float* gq_W3 = (const float*)d_in[30];
  const float* gq_b3 = (const float*)d_in[31];
  const float* gq_g  = (const float*)d_in[32];
  const float* gq_be = (const float*)d_in[33];

  const int N = in_sizes[0] / 10;          // 500000
  float* xs = (float*)d_out;               // x state in d_out[0 .. N*20)
  float* u  = xs + (size_t)N * 20;         // u in d_out tail (NG*20)

  float* part  = (float*)d_ws;             // NG*80 (4 slots x 20 per graph)
  float* gu    = part + NG * 80;           // NG*40 (merged nm|gp table)
  float* wpack = gu + NG * 40;             // L*2560 packed k_node weights

  const int L = 20;
  const int nblk = (N + 255) / 256;
  const int ngrid = nblk < 1792 ? nblk : 1792;   // measured residency capacity

  k_prelayer<<<(NG * 80) / 256, 256, 0, stream>>>(u, part, gu, nm_b1, gp_b1);
  k_pack<<<(L * 2560 + 255) / 256, 256, 0, stream>>>(wpack,
      nm_W1, nm_W2, nm_W3, nm_b2, nm_b3, nm_g, nm_be,
      gp_W1, gp_W2, gp_W3, gp_b2, gp_b3, gp_g, gp_be);
  k_init<<<nblk, 256, 0, stream>>>(x_in, xs, ni_W1, ni_b1, ni_W2, ni_b2,
                                   ni_W3, ni_b3, ni_g, ni_be, N);
  for (int l = 0; l < L; l++) {
    k_node<<<ngrid, 256, 0, stream>>>(batch, xs, (float*)d_ws,
                                      wpack + (size_t)l * 2560, N);
    int has_next = (l < L - 1);
    k_global<<<(NG * 4) / 128, 128, 0, stream>>>(u, part, gu,
        gq_W1 + (size_t)l * 800, gq_b1 + l * 20,
        gq_W2 + (size_t)l * 400, gq_b2 + l * 20,
        gq_W3 + (size_t)l * 400, gq_b3 + l * 20,
        gq_g + l * 20, gq_be + l * 20,
        nm_W1 + (size_t)(l + 1) * 800 + 400, nm_b1 + (l + 1) * 20,
        gp_W1 + (size_t)(l + 1) * 800 + 400, gp_b1 + (l + 1) * 20,
        has_next);
  }
}

// Round 12
// 1458.537 us; speedup vs baseline: 2.6757x; 1.1982x over previous
//
#include <hip/hip_runtime.h>

#define NG 8192
#define LN_EPS 1e-5f

typedef float v2f __attribute__((ext_vector_type(2)));

// ---------------- DPP wave-scan helpers (VALU-only, no LDS pipe) ----------------

__device__ __forceinline__ float wscan_add(float x) {
  x += __int_as_float(__builtin_amdgcn_update_dpp(0, __float_as_int(x), 0x111, 0xF, 0xF, true));
  x += __int_as_float(__builtin_amdgcn_update_dpp(0, __float_as_int(x), 0x112, 0xF, 0xF, true));
  x += __int_as_float(__builtin_amdgcn_update_dpp(0, __float_as_int(x), 0x114, 0xF, 0xF, true));
  x += __int_as_float(__builtin_amdgcn_update_dpp(0, __float_as_int(x), 0x118, 0xF, 0xF, true));
  x += __int_as_float(__builtin_amdgcn_update_dpp(0, __float_as_int(x), 0x142, 0xA, 0xF, false));
  x += __int_as_float(__builtin_amdgcn_update_dpp(0, __float_as_int(x), 0x143, 0xC, 0xF, false));
  return x;
}

__device__ __forceinline__ int wscan_max(int x) {
  int t;
  t = __builtin_amdgcn_update_dpp(0, x, 0x111, 0xF, 0xF, true); x = max(x, t);
  t = __builtin_amdgcn_update_dpp(0, x, 0x112, 0xF, 0xF, true); x = max(x, t);
  t = __builtin_amdgcn_update_dpp(0, x, 0x114, 0xF, 0xF, true); x = max(x, t);
  t = __builtin_amdgcn_update_dpp(0, x, 0x118, 0xF, 0xF, true); x = max(x, t);
  t = __builtin_amdgcn_update_dpp(0, x, 0x142, 0xA, 0xF, false); x = max(x, t);
  t = __builtin_amdgcn_update_dpp(0, x, 0x143, 0xC, 0xF, false); x = max(x, t);
  return x;
}

// ---------------- misc helpers ----------------

__device__ __forceinline__ void stage4(float* dst, const float* __restrict__ src,
                                       int n4, int tid, int nt) {
  float4* d = (float4*)dst;
  const float4* s = (const float4*)src;
  for (int t = tid; t < n4; t += nt) d[t] = s[t];
}

__device__ __forceinline__ void load20v(const float* __restrict__ p, v2f v[10]) {
  const float4* q = (const float4*)p;
#pragma unroll
  for (int t = 0; t < 5; t++) {
    float4 f = q[t];
    v[2*t]   = (v2f){f.x, f.y};
    v[2*t+1] = (v2f){f.z, f.w};
  }
}

__device__ __forceinline__ void store20v(float* __restrict__ p, const v2f v[10]) {
  float4* q = (float4*)p;
#pragma unroll
  for (int t = 0; t < 5; t++)
    q[t] = make_float4(v[2*t].x, v[2*t].y, v[2*t+1].x, v[2*t+1].y);
}

__device__ __forceinline__ float elem(const v2f* a, int k) { return a[k >> 1][k & 1]; }

// LN(relu(relu(h1)@W2+b2)@W3+b3)*g+be — packed fp32 pairs. Works for both
// global (SGPR s_load) and LDS (broadcast ds_read) weight pointers (inlined).
__device__ __forceinline__ void mlp23_ln1(
    const float* __restrict__ W2, const float* __restrict__ b2,
    const float* __restrict__ W3, const float* __restrict__ b3,
    const float* __restrict__ g,  const float* __restrict__ be,
    const v2f h1[10], v2f out[10]) {
  const v2f* W2v = (const v2f*)W2; const v2f* b2v = (const v2f*)b2;
  const v2f* W3v = (const v2f*)W3; const v2f* b3v = (const v2f*)b3;
  const v2f* gv  = (const v2f*)g;  const v2f* bev = (const v2f*)be;
  v2f h2[10];
#pragma unroll
  for (int j = 0; j < 10; j++) h2[j] = b2v[j];
#pragma unroll
  for (int k = 0; k < 20; k++) {
    float a = fmaxf(elem(h1, k), 0.0f); v2f av = {a, a};
#pragma unroll
    for (int j = 0; j < 10; j++) h2[j] += av * W2v[k*10 + j];
  }
  v2f h3[10];
#pragma unroll
  for (int j = 0; j < 10; j++) h3[j] = b3v[j];
#pragma unroll
  for (int k = 0; k < 20; k++) {
    float a = fmaxf(elem(h2, k), 0.0f); v2f av = {a, a};
#pragma unroll
    for (int j = 0; j < 10; j++) h3[j] += av * W3v[k*10 + j];
  }
  float mu = 0.0f;
#pragma unroll
  for (int j = 0; j < 10; j++) mu += h3[j].x + h3[j].y;
  mu *= 0.05f;
  float var = 0.0f;
#pragma unroll
  for (int j = 0; j < 10; j++) {
    float dx = h3[j].x - mu, dy = h3[j].y - mu;
    var += dx*dx + dy*dy;
  }
  var *= 0.05f;
  float rs = rsqrtf(var + LN_EPS);
  v2f muv = {mu, mu}, rsv = {rs, rs};
#pragma unroll
  for (int j = 0; j < 10; j++) out[j] = (h3[j] - muv) * rsv * gv[j] + bev[j];
}

// ---------------- kernels ----------------

__global__ __launch_bounds__(256) void k_prelayer(
    float* __restrict__ u, float* __restrict__ part, float* __restrict__ gu,
    const float* __restrict__ nmb1, const float* __restrict__ gpb1) {
  int t = blockIdx.x * 256 + threadIdx.x;   // NG*80 threads
  part[t] = 0.0f;
  if (t < NG * 40) {
    int j = t % 40;
    gu[t] = (j < 20) ? nmb1[j] : gpb1[j - 20];
  }
  if (t < NG * 20) u[t] = 0.0f;
}

// One-time weight packer: per layer l, blob of 2560 floats =
// [nmW1x 400][nmW2 400][nmW3 400][nmb2 20][nmb3 20][nmg 20][nmbe 20] (=1280)
// [gpW1x 400][gpW2 400][gpW3 400][gpb2 20][gpb3 20][gpg 20][gpbe 20] (=1280)
__global__ __launch_bounds__(256) void k_pack(
    float* __restrict__ wp,
    const float* __restrict__ nmW1, const float* __restrict__ nmW2,
    const float* __restrict__ nmW3, const float* __restrict__ nmb2,
    const float* __restrict__ nmb3, const float* __restrict__ nmg,
    const float* __restrict__ nmbe,
    const float* __restrict__ gpW1, const float* __restrict__ gpW2,
    const float* __restrict__ gpW3, const float* __restrict__ gpb2,
    const float* __restrict__ gpb3, const float* __restrict__ gpg,
    const float* __restrict__ gpbe) {
  int t = blockIdx.x * 256 + threadIdx.x;
  if (t >= 20 * 2560) return;
  int l = t / 2560, r = t % 2560;
  int half = (r >= 1280) ? 1 : 0;
  int rr = r - half * 1280;
  float v;
  if (rr < 400)       v = (half ? gpW1 : nmW1)[l * 800 + rr];       // x-rows only
  else if (rr < 800)  v = (half ? gpW2 : nmW2)[l * 400 + rr - 400];
  else if (rr < 1200) v = (half ? gpW3 : nmW3)[l * 400 + rr - 800];
  else if (rr < 1220) v = (half ? gpb2 : nmb2)[l * 20 + rr - 1200];
  else if (rr < 1240) v = (half ? gpb3 : nmb3)[l * 20 + rr - 1220];
  else if (rr < 1260) v = (half ? gpg  : nmg )[l * 20 + rr - 1240];
  else                v = (half ? gpbe : nmbe)[l * 20 + rr - 1260];
  wp[t] = v;
}

__global__ __launch_bounds__(256) void k_init(
    const float* __restrict__ xin, float* __restrict__ xs,
    const float* __restrict__ W1, const float* __restrict__ b1,
    const float* __restrict__ W2, const float* __restrict__ b2,
    const float* __restrict__ W3, const float* __restrict__ b3,
    const float* __restrict__ gw, const float* __restrict__ bw, int n) {
  int i = blockIdx.x * 256 + threadIdx.x;
  if (i >= n) return;
  float xi[10];
  const float2* xp = (const float2*)(xin + (size_t)i * 10);
#pragma unroll
  for (int t = 0; t < 5; t++) { float2 f = xp[t]; xi[t*2] = f.x; xi[t*2+1] = f.y; }
  const v2f* W1v = (const v2f*)W1; const v2f* b1v = (const v2f*)b1;
  v2f h1[10];
#pragma unroll
  for (int j = 0; j < 10; j++) h1[j] = b1v[j];
#pragma unroll
  for (int k = 0; k < 10; k++) {
    float a = xi[k]; v2f av = {a, a};
#pragma unroll
    for (int j = 0; j < 10; j++) h1[j] += av * W1v[k*10 + j];
  }
  v2f out[10];
  mlp23_ln1(W2, b2, W3, b3, gw, bw, h1, out);
  store20v(xs + (size_t)i * 20, out);
}

// Per-layer node kernel — r8 structure (grid 1954, natural codegen, no
// attributes, no tail tricks: r9-r11 proved those axes dead) with ONE change:
// ALL weights (nm + gp, packed 2560-float blob) staged into LDS and read as
// broadcast ds_read_b128. Rationale (r11 post-mortem): the straggler
// generation's cost IS the body's latency chain at low concurrency, and that
// chain is dominated by the nm s_load stream's serial SGPR-window round
// trips (~300cy each, unhidden without TLP). ds_read pipelines deeply
// (lgkmcnt window, ~120cy) -> straggler tau should collapse. Also removes
// the s_load/ds_read lgkmcnt mixing in the main body. Differs from r4 (74us)
// by NOT forcing (256,8) -> no VGPR crush, no scratch spills. LDS 10240B ->
// blocks/CU still min(7-cap, 15) = 7. Tripwire: dur >= 51us -> straggler is
// not weight-chain-bound; restore r8 and conclude.
// Aggregation: deterministic DPP scan + run-end slot stores (no atomics).
__global__ __launch_bounds__(256) void k_node(
    const int* __restrict__ batch, float* __restrict__ xs,
    float* __restrict__ ws, const float* __restrict__ wl, int n) {
  float* part = ws;                         // NG*80
  const float* gu = ws + NG * 80;           // NG*40
  __shared__ float sm[2560];
  int tid = threadIdx.x;
  stage4(sm, wl, 640, tid, 256);            // whole packed blob, contiguous
  __syncthreads();

  int i = blockIdx.x * 256 + tid;
  int lane = tid & 63;
  bool valid = i < n;
  int ic = valid ? i : (n - 1);
  int b = batch[ic];

  v2f x[10];
  load20v(xs + (size_t)ic * 20, x);

  // ---- NodeModel: h1 = x@W1x + gu_nm[b]  (gu = u@W1u + b1, prefolded) ----
  v2f h1[10];
  load20v(gu + (size_t)b * 40, h1);
  const v2f* W1v = (const v2f*)sm;
#pragma unroll
  for (int k = 0; k < 20; k++) {
    float a = elem(x, k); v2f av = {a, a};
#pragma unroll
    for (int j = 0; j < 10; j++) h1[j] += av * W1v[k*10 + j];
  }
  v2f xn[10];
  mlp23_ln1(sm + 400, sm + 1200, sm + 800, sm + 1220, sm + 1240, sm + 1260,
            h1, xn);
#pragma unroll
  for (int j = 0; j < 10; j++) xn[j] += x[j];     // residual
  if (valid) store20v(xs + (size_t)ic * 20, xn);

  // ---- pre-aggr MLP on updated x (weights from LDS broadcast) ----
  v2f p1[10];
  load20v(gu + (size_t)b * 40 + 20, p1);
  const v2f* G1v = (const v2f*)(sm + 1280);
#pragma unroll
  for (int k = 0; k < 20; k++) {
    float a = elem(xn, k); v2f av = {a, a};
#pragma unroll
    for (int j = 0; j < 10; j++) p1[j] += av * G1v[k*10 + j];
  }
  v2f pre[10];
  mlp23_ln1(sm + 1680, sm + 2480, sm + 2080, sm + 2500, sm + 2520, sm + 2540,
            p1, pre);

  // ---- aggregation: DPP scan + run-end slot stores (batch sorted) ----
  int key = valid ? b : -1;
  if (!valid) {
#pragma unroll
    for (int j = 0; j < 10; j++) pre[j] = (v2f){0.0f, 0.0f};
  }
  int pk = __builtin_amdgcn_update_dpp(-1, key, 0x138, 0xF, 0xF, false);
  int nk = __builtin_amdgcn_update_dpp(-2, key, 0x130, 0xF, 0xF, false);
  bool isstart = (key != pk);
  int st = wscan_max(isstart ? lane : 0);   // start lane of my run

#pragma unroll
  for (int j = 0; j < 10; j++) {
    pre[j].x = wscan_add(pre[j].x);
    pre[j].y = wscan_add(pre[j].y);
  }

  int pl = (st > 0) ? (st - 1) : 0;
  float use = (st > 0) ? 1.0f : 0.0f;
  v2f fl[10];
#pragma unroll
  for (int j = 0; j < 10; j++) {
    float bx = __shfl(pre[j].x, pl);
    float by = __shfl(pre[j].y, pl);
    fl[j].x = pre[j].x - use * bx;
    fl[j].y = pre[j].y - use * by;
  }
  bool runend = valid && (nk != key);       // lane63 gets nk=-2 -> true
  if (runend) {
    int slot = (i >> 6) & 3;                // graphs span <=4 consecutive waves
    float* pp = part + (size_t)b * 80 + slot * 20;
#pragma unroll
    for (int j = 0; j < 10; j++) {
      pp[2*j]     = fl[j].x;
      pp[2*j + 1] = fl[j].y;
    }
  }
}

// Per-layer global kernel, 4 LANES PER GRAPH (NG*4 threads): coalesced slot
// loads, fixed-tree shfl butterflies, transposed weights in LDS. No slot
// re-zero needed — batch is constant across layers, so exactly the same
// (graph, slot) pairs are rewritten every layer; slots never written stay
// at their k_prelayer zeros.
__global__ __launch_bounds__(128) void k_global(
    float* __restrict__ u, float* __restrict__ part, float* __restrict__ gu,
    const float* __restrict__ qW1, const float* __restrict__ qb1,
    const float* __restrict__ qW2, const float* __restrict__ qb2,
    const float* __restrict__ qW3, const float* __restrict__ qb3,
    const float* __restrict__ qg,  const float* __restrict__ qbe,
    const float* __restrict__ nmW1u, const float* __restrict__ nmb1n,
    const float* __restrict__ gpW1u, const float* __restrict__ gpb1n,
    int has_next) {
  __shared__ float sW1T[20 * 40];   // [j][k], k over (agg | u)
  __shared__ float sW2T[20 * 20];   // [j][k]
  __shared__ float sW3T[20 * 20];
  __shared__ float sNT[20 * 20];    // nmW1u^T (next layer)
  __shared__ float sGT[20 * 20];    // gpW1u^T (next layer)
  __shared__ float sB[140];         // qb1|qb2|qb3|qg|qbe|nmb1n|gpb1n
  int tid = threadIdx.x;
  for (int e = tid; e < 800; e += 128) sW1T[(e % 20) * 40 + (e / 20)] = qW1[e];
  for (int e = tid; e < 400; e += 128) {
    int k = e / 20, j = e % 20;
    sW2T[j * 20 + k] = qW2[e];
    sW3T[j * 20 + k] = qW3[e];
    sNT[j * 20 + k]  = nmW1u[e];
    sGT[j * 20 + k]  = gpW1u[e];
  }
  if (tid < 20) {
    sB[tid]       = qb1[tid];
    sB[20 + tid]  = qb2[tid];
    sB[40 + tid]  = qb3[tid];
    sB[60 + tid]  = qg[tid];
    sB[80 + tid]  = qbe[tid];
    sB[100 + tid] = nmb1n[tid];
    sB[120 + tid] = gpb1n[tid];
  }
  __syncthreads();

  int t = blockIdx.x * 128 + tid;   // exactly NG*4 threads
  int g = t >> 2;                   // graph
  int q = t & 3;                    // quarter: output cols [q*5, q*5+5)
  int lane = tid & 63;
  int gl = lane & ~3;               // group base lane (groups never cross waves)

  // my partial slot (coalesced 80B/lane), then fixed-tree butterfly sum
  float a[20];
  {
    const float4* p = (const float4*)(part + (size_t)g * 80 + q * 20);
#pragma unroll
    for (int i = 0; i < 5; i++) {
      float4 f = p[i];
      a[4*i] = f.x; a[4*i+1] = f.y; a[4*i+2] = f.z; a[4*i+3] = f.w;
    }
  }
#pragma unroll
  for (int i = 0; i < 20; i++) {
    a[i] += __shfl_xor(a[i], 1);
    a[i] += __shfl_xor(a[i], 2);    // (s0+s1)+(s2+s3), same on all 4 lanes
  }

  float uu[20];
  {
    const float4* p = (const float4*)(u + (size_t)g * 20);
#pragma unroll
    for (int i = 0; i < 5; i++) {
      float4 f = p[i];
      uu[4*i] = f.x; uu[4*i+1] = f.y; uu[4*i+2] = f.z; uu[4*i+3] = f.w;
    }
  }

  // h1 slice: j = q*5+o ; h1_j = qb1[j] + a.W1[:,j](rows 0..19) + uu.W1[:,j](rows 20..39)
  float h1[5];
#pragma unroll
  for (int o = 0; o < 5; o++) {
    int j = q * 5 + o;
    const v2f* w = (const v2f*)(sW1T + j * 40);
    v2f acc = {0.0f, 0.0f};
#pragma unroll
    for (int kk = 0; kk < 10; kk++) acc += (v2f){a[2*kk], a[2*kk+1]} * w[kk];
#pragma unroll
    for (int kk = 0; kk < 10; kk++) acc += (v2f){uu[2*kk], uu[2*kk+1]} * w[10 + kk];
    h1[o] = sB[j] + acc.x + acc.y;
  }

  // gather relu(h1) across the 4-lane group (static unroll -> static reg idx)
  float r1[20];
#pragma unroll
  for (int k = 0; k < 20; k++)
    r1[k] = fmaxf(__shfl(h1[k % 5], gl + (k / 5)), 0.0f);

  float h2[5];
#pragma unroll
  for (int o = 0; o < 5; o++) {
    int j = q * 5 + o;
    const v2f* w = (const v2f*)(sW2T + j * 20);
    v2f acc = {0.0f, 0.0f};
#pragma unroll
    for (int kk = 0; kk < 10; kk++) acc += (v2f){r1[2*kk], r1[2*kk+1]} * w[kk];
    h2[o] = sB[20 + j] + acc.x + acc.y;
  }

  float r2[20];
#pragma unroll
  for (int k = 0; k < 20; k++)
    r2[k] = fmaxf(__shfl(h2[k % 5], gl + (k / 5)), 0.0f);

  float h3[5];
#pragma unroll
  for (int o = 0; o < 5; o++) {
    int j = q * 5 + o;
    const v2f* w = (const v2f*)(sW3T + j * 20);
    v2f acc = {0.0f, 0.0f};
#pragma unroll
    for (int kk = 0; kk < 10; kk++) acc += (v2f){r2[2*kk], r2[2*kk+1]} * w[kk];
    h3[o] = sB[40 + j] + acc.x + acc.y;
  }

  // group LayerNorm (fixed-tree butterflies)
  float s = h3[0] + h3[1] + h3[2] + h3[3] + h3[4];
  s += __shfl_xor(s, 1);
  s += __shfl_xor(s, 2);
  float mu = s * 0.05f;
  float d = 0.0f;
#pragma unroll
  for (int o = 0; o < 5; o++) { float dd = h3[o] - mu; d += dd * dd; }
  d += __shfl_xor(d, 1);
  d += __shfl_xor(d, 2);
  float rs = rsqrtf(d * 0.05f + LN_EPS);

  float un[5];
#pragma unroll
  for (int o = 0; o < 5; o++) {
    int j = q * 5 + o;
    un[o] = (h3[o] - mu) * rs * sB[60 + j] + sB[80 + j] + uu[j];  // +residual
  }
#pragma unroll
  for (int o = 0; o < 5; o++) u[(size_t)g * 20 + q * 5 + o] = un[o];

  if (has_next) {
    float ru[20];
#pragma unroll
    for (int k = 0; k < 20; k++)
      ru[k] = __shfl(un[k % 5], gl + (k / 5));
    float gn[5], gg[5];
#pragma unroll
    for (int o = 0; o < 5; o++) {
      int j = q * 5 + o;
      const v2f* wn = (const v2f*)(sNT + j * 20);
      const v2f* wg = (const v2f*)(sGT + j * 20);
      v2f an = {0.0f, 0.0f}, ag = {0.0f, 0.0f};
#pragma unroll
      for (int kk = 0; kk < 10; kk++) {
        v2f rv = {ru[2*kk], ru[2*kk+1]};
        an += rv * wn[kk];
        ag += rv * wg[kk];
      }
      gn[o] = sB[100 + j] + an.x + an.y;
      gg[o] = sB[120 + j] + ag.x + ag.y;
    }
#pragma unroll
    for (int o = 0; o < 5; o++) {
      gu[(size_t)g * 40 + q * 5 + o]      = gn[o];
      gu[(size_t)g * 40 + 20 + q * 5 + o] = gg[o];
    }
  }
}

// ---------------- host launcher ----------------

extern "C" void kernel_launch(void* const* d_in, const int* in_sizes, int n_in,
                              void* d_out, int out_size, void* d_ws, size_t ws_size,
                              hipStream_t stream) {
  const float* x_in  = (const float*)d_in[0];
  const int*   batch = (const int*)  d_in[1];
  const float* ni_W1 = (const float*)d_in[2];
  const float* ni_b1 = (const float*)d_in[3];
  const float* ni_W2 = (const float*)d_in[4];
  const float* ni_b2 = (const float*)d_in[5];
  const float* ni_W3 = (const float*)d_in[6];
  const float* ni_b3 = (const float*)d_in[7];
  const float* ni_g  = (const float*)d_in[8];
  const float* ni_be = (const float*)d_in[9];
  const float* nm_W1 = (const float*)d_in[10];
  const float* nm_b1 = (const float*)d_in[11];
  const float* nm_W2 = (const float*)d_in[12];
  const float* nm_b2 = (const float*)d_in[13];
  const float* nm_W3 = (const float*)d_in[14];
  const float* nm_b3 = (const float*)d_in[15];
  const float* nm_g  = (const float*)d_in[16];
  const float* nm_be = (const float*)d_in[17];
  const float* gp_W1 = (const float*)d_in[18];
  const float* gp_b1 = (const float*)d_in[19];
  const float* gp_W2 = (const float*)d_in[20];
  const float* gp_b2 = (const float*)d_in[21];
  const float* gp_W3 = (const float*)d_in[22];
  const float* gp_b3 = (const float*)d_in[23];
  const float* gp_g  = (const float*)d_in[24];
  const float* gp_be = (const float*)d_in[25];
  const float* gq_W1 = (const float*)d_in[26];
  const float* gq_b1 = (const float*)d_in[27];
  const float* gq_W2 = (const float*)d_in[28];
  const float* gq_b2 = (const float*)d_in[29];
  const float* gq_W3 = (const float*)d_in[30];
  const float* gq_b3 = (const float*)d_in[31];
  const float* gq_g  = (const float*)d_in[32];
  const float* gq_be = (const float*)d_in[33];

  const int N = in_sizes[0] / 10;          // 500000
  float* xs = (float*)d_out;               // x state in d_out[0 .. N*20)
  float* u  = xs + (size_t)N * 20;         // u in d_out tail (NG*20)

  float* part  = (float*)d_ws;             // NG*80 (4 slots x 20 per graph)
  float* gu    = part + NG * 80;           // NG*40 (merged nm|gp table)
  float* wpack = gu + NG * 40;             // L*2560 packed k_node weights

  const int L = 20;
  const int nblk = (N + 255) / 256;

  k_prelayer<<<(NG * 80) / 256, 256, 0, stream>>>(u, part, gu, nm_b1, gp_b1);
  k_pack<<<(L * 2560 + 255) / 256, 256, 0, stream>>>(wpack,
      nm_W1, nm_W2, nm_W3, nm_b2, nm_b3, nm_g, nm_be,
      gp_W1, gp_W2, gp_W3, gp_b2, gp_b3, gp_g, gp_be);
  k_init<<<nblk, 256, 0, stream>>>(x_in, xs, ni_W1, ni_b1, ni_W2, ni_b2,
                                   ni_W3, ni_b3, ni_g, ni_be, N);
  for (int l = 0; l < L; l++) {
    k_node<<<nblk, 256, 0, stream>>>(batch, xs, (float*)d_ws,
                                     wpack + (size_t)l * 2560, N);
    int has_next = (l < L - 1);
    k_global<<<(NG * 4) / 128, 128, 0, stream>>>(u, part, gu,
        gq_W1 + (size_t)l * 800, gq_b1 + l * 20,
        gq_W2 + (size_t)l * 400, gq_b2 + l * 20,
        gq_W3 + (size_t)l * 400, gq_b3 + l * 20,
        gq_g + l * 20, gq_be + l * 20,
        nm_W1 + (size_t)(l + 1) * 800 + 400, nm_b1 + (l + 1) * 20,
        gp_W1 + (size_t)(l + 1) * 800 + 400, gp_b1 + (l + 1) * 20,
        has_next);
  }
}

// Round 13
// 1238.254 us; speedup vs baseline: 3.1517x; 1.1779x over previous
//
#include <hip/hip_runtime.h>

#define NG 8192
#define LN_EPS 1e-5f

typedef float v2f __attribute__((ext_vector_type(2)));

// ---------------- DPP wave-scan helpers (VALU-only, no LDS pipe) ----------------

__device__ __forceinline__ float wscan_add(float x) {
  x += __int_as_float(__builtin_amdgcn_update_dpp(0, __float_as_int(x), 0x111, 0xF, 0xF, true));
  x += __int_as_float(__builtin_amdgcn_update_dpp(0, __float_as_int(x), 0x112, 0xF, 0xF, true));
  x += __int_as_float(__builtin_amdgcn_update_dpp(0, __float_as_int(x), 0x114, 0xF, 0xF, true));
  x += __int_as_float(__builtin_amdgcn_update_dpp(0, __float_as_int(x), 0x118, 0xF, 0xF, true));
  x += __int_as_float(__builtin_amdgcn_update_dpp(0, __float_as_int(x), 0x142, 0xA, 0xF, false));
  x += __int_as_float(__builtin_amdgcn_update_dpp(0, __float_as_int(x), 0x143, 0xC, 0xF, false));
  return x;
}

__device__ __forceinline__ int wscan_max(int x) {
  int t;
  t = __builtin_amdgcn_update_dpp(0, x, 0x111, 0xF, 0xF, true); x = max(x, t);
  t = __builtin_amdgcn_update_dpp(0, x, 0x112, 0xF, 0xF, true); x = max(x, t);
  t = __builtin_amdgcn_update_dpp(0, x, 0x114, 0xF, 0xF, true); x = max(x, t);
  t = __builtin_amdgcn_update_dpp(0, x, 0x118, 0xF, 0xF, true); x = max(x, t);
  t = __builtin_amdgcn_update_dpp(0, x, 0x142, 0xA, 0xF, false); x = max(x, t);
  t = __builtin_amdgcn_update_dpp(0, x, 0x143, 0xC, 0xF, false); x = max(x, t);
  return x;
}

// ---------------- misc helpers ----------------

__device__ __forceinline__ void stage4(float* dst, const float* __restrict__ src,
                                       int n4, int tid, int nt) {
  float4* d = (float4*)dst;
  const float4* s = (const float4*)src;
  for (int t = tid; t < n4; t += nt) d[t] = s[t];
}

__device__ __forceinline__ void load20v(const float* __restrict__ p, v2f v[10]) {
  const float4* q = (const float4*)p;
#pragma unroll
  for (int t = 0; t < 5; t++) {
    float4 f = q[t];
    v[2*t]   = (v2f){f.x, f.y};
    v[2*t+1] = (v2f){f.z, f.w};
  }
}

__device__ __forceinline__ void store20v(float* __restrict__ p, const v2f v[10]) {
  float4* q = (float4*)p;
#pragma unroll
  for (int t = 0; t < 5; t++)
    q[t] = make_float4(v[2*t].x, v[2*t].y, v[2*t+1].x, v[2*t+1].y);
}

__device__ __forceinline__ float elem(const v2f* a, int k) { return a[k >> 1][k & 1]; }

// LN(relu(relu(h1)@W2+b2)@W3+b3)*g+be — packed fp32 pairs. Works for both
// global (SGPR s_load) and LDS (broadcast ds_read) weight pointers (inlined).
__device__ __forceinline__ void mlp23_ln1(
    const float* __restrict__ W2, const float* __restrict__ b2,
    const float* __restrict__ W3, const float* __restrict__ b3,
    const float* __restrict__ g,  const float* __restrict__ be,
    const v2f h1[10], v2f out[10]) {
  const v2f* W2v = (const v2f*)W2; const v2f* b2v = (const v2f*)b2;
  const v2f* W3v = (const v2f*)W3; const v2f* b3v = (const v2f*)b3;
  const v2f* gv  = (const v2f*)g;  const v2f* bev = (const v2f*)be;
  v2f h2[10];
#pragma unroll
  for (int j = 0; j < 10; j++) h2[j] = b2v[j];
#pragma unroll
  for (int k = 0; k < 20; k++) {
    float a = fmaxf(elem(h1, k), 0.0f); v2f av = {a, a};
#pragma unroll
    for (int j = 0; j < 10; j++) h2[j] += av * W2v[k*10 + j];
  }
  v2f h3[10];
#pragma unroll
  for (int j = 0; j < 10; j++) h3[j] = b3v[j];
#pragma unroll
  for (int k = 0; k < 20; k++) {
    float a = fmaxf(elem(h2, k), 0.0f); v2f av = {a, a};
#pragma unroll
    for (int j = 0; j < 10; j++) h3[j] += av * W3v[k*10 + j];
  }
  float mu = 0.0f;
#pragma unroll
  for (int j = 0; j < 10; j++) mu += h3[j].x + h3[j].y;
  mu *= 0.05f;
  float var = 0.0f;
#pragma unroll
  for (int j = 0; j < 10; j++) {
    float dx = h3[j].x - mu, dy = h3[j].y - mu;
    var += dx*dx + dy*dy;
  }
  var *= 0.05f;
  float rs = rsqrtf(var + LN_EPS);
  v2f muv = {mu, mu}, rsv = {rs, rs};
#pragma unroll
  for (int j = 0; j < 10; j++) out[j] = (h3[j] - muv) * rsv * gv[j] + bev[j];
}

// ---------------- kernels ----------------

__global__ __launch_bounds__(256) void k_prelayer(
    float* __restrict__ u, float* __restrict__ part, float* __restrict__ gu,
    const float* __restrict__ nmb1, const float* __restrict__ gpb1) {
  int t = blockIdx.x * 256 + threadIdx.x;   // NG*80 threads
  part[t] = 0.0f;
  if (t < NG * 40) {
    int j = t % 40;
    gu[t] = (j < 20) ? nmb1[j] : gpb1[j - 20];
  }
  if (t < NG * 20) u[t] = 0.0f;
}

// One-time weight packer: per layer l, blob of 2560 floats =
// [nmW1x 400][nmW2 400][nmW3 400][nmb2 20][nmb3 20][nmg 20][nmbe 20] (=1280)
// [gpW1x 400][gpW2 400][gpW3 400][gpb2 20][gpb3 20][gpg 20][gpbe 20] (=1280)
__global__ __launch_bounds__(256) void k_pack(
    float* __restrict__ wp,
    const float* __restrict__ nmW1, const float* __restrict__ nmW2,
    const float* __restrict__ nmW3, const float* __restrict__ nmb2,
    const float* __restrict__ nmb3, const float* __restrict__ nmg,
    const float* __restrict__ nmbe,
    const float* __restrict__ gpW1, const float* __restrict__ gpW2,
    const float* __restrict__ gpW3, const float* __restrict__ gpb2,
    const float* __restrict__ gpb3, const float* __restrict__ gpg,
    const float* __restrict__ gpbe) {
  int t = blockIdx.x * 256 + threadIdx.x;
  if (t >= 20 * 2560) return;
  int l = t / 2560, r = t % 2560;
  int half = (r >= 1280) ? 1 : 0;
  int rr = r - half * 1280;
  float v;
  if (rr < 400)       v = (half ? gpW1 : nmW1)[l * 800 + rr];       // x-rows only
  else if (rr < 800)  v = (half ? gpW2 : nmW2)[l * 400 + rr - 400];
  else if (rr < 1200) v = (half ? gpW3 : nmW3)[l * 400 + rr - 800];
  else if (rr < 1220) v = (half ? gpb2 : nmb2)[l * 20 + rr - 1200];
  else if (rr < 1240) v = (half ? gpb3 : nmb3)[l * 20 + rr - 1220];
  else if (rr < 1260) v = (half ? gpg  : nmg )[l * 20 + rr - 1240];
  else                v = (half ? gpbe : nmbe)[l * 20 + rr - 1260];
  wp[t] = v;
}

__global__ __launch_bounds__(256) void k_init(
    const float* __restrict__ xin, float* __restrict__ xs,
    const float* __restrict__ W1, const float* __restrict__ b1,
    const float* __restrict__ W2, const float* __restrict__ b2,
    const float* __restrict__ W3, const float* __restrict__ b3,
    const float* __restrict__ gw, const float* __restrict__ bw, int n) {
  int i = blockIdx.x * 256 + threadIdx.x;
  if (i >= n) return;
  float xi[10];
  const float2* xp = (const float2*)(xin + (size_t)i * 10);
#pragma unroll
  for (int t = 0; t < 5; t++) { float2 f = xp[t]; xi[t*2] = f.x; xi[t*2+1] = f.y; }
  const v2f* W1v = (const v2f*)W1; const v2f* b1v = (const v2f*)b1;
  v2f h1[10];
#pragma unroll
  for (int j = 0; j < 10; j++) h1[j] = b1v[j];
#pragma unroll
  for (int k = 0; k < 10; k++) {
    float a = xi[k]; v2f av = {a, a};
#pragma unroll
    for (int j = 0; j < 10; j++) h1[j] += av * W1v[k*10 + j];
  }
  v2f out[10];
  mlp23_ln1(W2, b2, W3, b3, gw, bw, h1, out);
  store20v(xs + (size_t)i * 20, out);
}

// Per-layer node kernel — FINAL (round-8 configuration, best measured:
// k_node 50.9us, total 1255us). 1 node/thread, pk-fp32; nm weights stream
// via s_load (SGPR operands, single packed base), gp blob staged per-block
// into LDS (broadcast ds_read_b128, conflict-free). Aggregation:
// deterministic DPP scan + run-end slot stores (no atomics).
//
// Session conclusions (r0-r12, documented for future work):
// - The wall is a two-generation dispatch: grid 1954 > ~1792 resident
//   capacity (~7 blocks/CU); the 162-block straggler generation costs a
//   full ~25us body-latency chain. Per-wave residency is invariant ~26us
//   across ALL variants tried (occupancy x time integral constant).
// - Dead axes (all measured): SGPR caps 112/96/80 (no residency change);
//   forced launch_bounds (VGPR crush -> scratch spills, r3/r4); grid-fit +
//   grid-stride loop (LICM hoists weight stream into VGPR 36->256, r9);
//   wave-granular tail, fenced (tail phase still pays the latency chain at
//   low occupancy, r10/r11); all-LDS weights (main gen slows 25%, r12).
// - Remaining headroom would need bf16-MFMA restructure of the MLPs
//   (MfmaUtil currently 0) or a residency lever not reachable from source.
__global__ __launch_bounds__(256) __attribute__((amdgpu_num_sgpr(80)))
void k_node(
    const int* __restrict__ batch, float* __restrict__ xs,
    float* __restrict__ ws, const float* __restrict__ wl, int n) {
  float* part = ws;                         // NG*80
  const float* gu = ws + NG * 80;           // NG*40
  __shared__ float sm[1280];
  int tid = threadIdx.x;
  stage4(sm, wl + 1280, 320, tid, 256);     // whole gp blob, contiguous
  __syncthreads();

  int i = blockIdx.x * 256 + tid;
  int lane = tid & 63;
  bool valid = i < n;
  int ic = valid ? i : (n - 1);
  int b = batch[ic];

  v2f x[10];
  load20v(xs + (size_t)ic * 20, x);

  // ---- NodeModel: h1 = x@W1x + gu_nm[b]  (gu = u@W1u + b1, prefolded) ----
  v2f h1[10];
  load20v(gu + (size_t)b * 40, h1);
  const v2f* W1v = (const v2f*)wl;
#pragma unroll
  for (int k = 0; k < 20; k++) {
    float a = elem(x, k); v2f av = {a, a};
#pragma unroll
    for (int j = 0; j < 10; j++) h1[j] += av * W1v[k*10 + j];
  }
  v2f xn[10];
  mlp23_ln1(wl + 400, wl + 1200, wl + 800, wl + 1220, wl + 1240, wl + 1260,
            h1, xn);
#pragma unroll
  for (int j = 0; j < 10; j++) xn[j] += x[j];     // residual
  if (valid) store20v(xs + (size_t)ic * 20, xn);

  // ---- pre-aggr MLP on updated x (weights from LDS broadcast) ----
  v2f p1[10];
  load20v(gu + (size_t)b * 40 + 20, p1);
  const v2f* G1v = (const v2f*)sm;
#pragma unroll
  for (int k = 0; k < 20; k++) {
    float a = elem(xn, k); v2f av = {a, a};
#pragma unroll
    for (int j = 0; j < 10; j++) p1[j] += av * G1v[k*10 + j];
  }
  v2f pre[10];
  mlp23_ln1(sm + 400, sm + 1200, sm + 800, sm + 1220, sm + 1240, sm + 1260,
            p1, pre);

  // ---- aggregation: DPP scan + run-end slot stores (batch sorted) ----
  int key = valid ? b : -1;
  if (!valid) {
#pragma unroll
    for (int j = 0; j < 10; j++) pre[j] = (v2f){0.0f, 0.0f};
  }
  int pk = __builtin_amdgcn_update_dpp(-1, key, 0x138, 0xF, 0xF, false);
  int nk = __builtin_amdgcn_update_dpp(-2, key, 0x130, 0xF, 0xF, false);
  bool isstart = (key != pk);
  int st = wscan_max(isstart ? lane : 0);   // start lane of my run

#pragma unroll
  for (int j = 0; j < 10; j++) {
    pre[j].x = wscan_add(pre[j].x);
    pre[j].y = wscan_add(pre[j].y);
  }

  int pl = (st > 0) ? (st - 1) : 0;
  float use = (st > 0) ? 1.0f : 0.0f;
  v2f fl[10];
#pragma unroll
  for (int j = 0; j < 10; j++) {
    float bx = __shfl(pre[j].x, pl);
    float by = __shfl(pre[j].y, pl);
    fl[j].x = pre[j].x - use * bx;
    fl[j].y = pre[j].y - use * by;
  }
  bool runend = valid && (nk != key);       // lane63 gets nk=-2 -> true
  if (runend) {
    int slot = (i >> 6) & 3;                // graphs span <=4 consecutive waves
    float* pp = part + (size_t)b * 80 + slot * 20;
#pragma unroll
    for (int j = 0; j < 10; j++) {
      pp[2*j]     = fl[j].x;
      pp[2*j + 1] = fl[j].y;
    }
  }
}

// Per-layer global kernel, 4 LANES PER GRAPH (NG*4 threads): coalesced slot
// loads, fixed-tree shfl butterflies, transposed weights in LDS. No slot
// re-zero needed — batch is constant across layers, so exactly the same
// (graph, slot) pairs are rewritten every layer; slots never written stay
// at their k_prelayer zeros.
__global__ __launch_bounds__(128) void k_global(
    float* __restrict__ u, float* __restrict__ part, float* __restrict__ gu,
    const float* __restrict__ qW1, const float* __restrict__ qb1,
    const float* __restrict__ qW2, const float* __restrict__ qb2,
    const float* __restrict__ qW3, const float* __restrict__ qb3,
    const float* __restrict__ qg,  const float* __restrict__ qbe,
    const float* __restrict__ nmW1u, const float* __restrict__ nmb1n,
    const float* __restrict__ gpW1u, const float* __restrict__ gpb1n,
    int has_next) {
  __shared__ float sW1T[20 * 40];   // [j][k], k over (agg | u)
  __shared__ float sW2T[20 * 20];   // [j][k]
  __shared__ float sW3T[20 * 20];
  __shared__ float sNT[20 * 20];    // nmW1u^T (next layer)
  __shared__ float sGT[20 * 20];    // gpW1u^T (next layer)
  __shared__ float sB[140];         // qb1|qb2|qb3|qg|qbe|nmb1n|gpb1n
  int tid = threadIdx.x;
  for (int e = tid; e < 800; e += 128) sW1T[(e % 20) * 40 + (e / 20)] = qW1[e];
  for (int e = tid; e < 400; e += 128) {
    int k = e / 20, j = e % 20;
    sW2T[j * 20 + k] = qW2[e];
    sW3T[j * 20 + k] = qW3[e];
    sNT[j * 20 + k]  = nmW1u[e];
    sGT[j * 20 + k]  = gpW1u[e];
  }
  if (tid < 20) {
    sB[tid]       = qb1[tid];
    sB[20 + tid]  = qb2[tid];
    sB[40 + tid]  = qb3[tid];
    sB[60 + tid]  = qg[tid];
    sB[80 + tid]  = qbe[tid];
    sB[100 + tid] = nmb1n[tid];
    sB[120 + tid] = gpb1n[tid];
  }
  __syncthreads();

  int t = blockIdx.x * 128 + tid;   // exactly NG*4 threads
  int g = t >> 2;                   // graph
  int q = t & 3;                    // quarter: output cols [q*5, q*5+5)
  int lane = tid & 63;
  int gl = lane & ~3;               // group base lane (groups never cross waves)

  // my partial slot (coalesced 80B/lane), then fixed-tree butterfly sum
  float a[20];
  {
    const float4* p = (const float4*)(part + (size_t)g * 80 + q * 20);
#pragma unroll
    for (int i = 0; i < 5; i++) {
      float4 f = p[i];
      a[4*i] = f.x; a[4*i+1] = f.y; a[4*i+2] = f.z; a[4*i+3] = f.w;
    }
  }
#pragma unroll
  for (int i = 0; i < 20; i++) {
    a[i] += __shfl_xor(a[i], 1);
    a[i] += __shfl_xor(a[i], 2);    // (s0+s1)+(s2+s3), same on all 4 lanes
  }

  float uu[20];
  {
    const float4* p = (const float4*)(u + (size_t)g * 20);
#pragma unroll
    for (int i = 0; i < 5; i++) {
      float4 f = p[i];
      uu[4*i] = f.x; uu[4*i+1] = f.y; uu[4*i+2] = f.z; uu[4*i+3] = f.w;
    }
  }

  // h1 slice: j = q*5+o ; h1_j = qb1[j] + a.W1[:,j](rows 0..19) + uu.W1[:,j](rows 20..39)
  float h1[5];
#pragma unroll
  for (int o = 0; o < 5; o++) {
    int j = q * 5 + o;
    const v2f* w = (const v2f*)(sW1T + j * 40);
    v2f acc = {0.0f, 0.0f};
#pragma unroll
    for (int kk = 0; kk < 10; kk++) acc += (v2f){a[2*kk], a[2*kk+1]} * w[kk];
#pragma unroll
    for (int kk = 0; kk < 10; kk++) acc += (v2f){uu[2*kk], uu[2*kk+1]} * w[10 + kk];
    h1[o] = sB[j] + acc.x + acc.y;
  }

  // gather relu(h1) across the 4-lane group (static unroll -> static reg idx)
  float r1[20];
#pragma unroll
  for (int k = 0; k < 20; k++)
    r1[k] = fmaxf(__shfl(h1[k % 5], gl + (k / 5)), 0.0f);

  float h2[5];
#pragma unroll
  for (int o = 0; o < 5; o++) {
    int j = q * 5 + o;
    const v2f* w = (const v2f*)(sW2T + j * 20);
    v2f acc = {0.0f, 0.0f};
#pragma unroll
    for (int kk = 0; kk < 10; kk++) acc += (v2f){r1[2*kk], r1[2*kk+1]} * w[kk];
    h2[o] = sB[20 + j] + acc.x + acc.y;
  }

  float r2[20];
#pragma unroll
  for (int k = 0; k < 20; k++)
    r2[k] = fmaxf(__shfl(h2[k % 5], gl + (k / 5)), 0.0f);

  float h3[5];
#pragma unroll
  for (int o = 0; o < 5; o++) {
    int j = q * 5 + o;
    const v2f* w = (const v2f*)(sW3T + j * 20);
    v2f acc = {0.0f, 0.0f};
#pragma unroll
    for (int kk = 0; kk < 10; kk++) acc += (v2f){r2[2*kk], r2[2*kk+1]} * w[kk];
    h3[o] = sB[40 + j] + acc.x + acc.y;
  }

  // group LayerNorm (fixed-tree butterflies)
  float s = h3[0] + h3[1] + h3[2] + h3[3] + h3[4];
  s += __shfl_xor(s, 1);
  s += __shfl_xor(s, 2);
  float mu = s * 0.05f;
  float d = 0.0f;
#pragma unroll
  for (int o = 0; o < 5; o++) { float dd = h3[o] - mu; d += dd * dd; }
  d += __shfl_xor(d, 1);
  d += __shfl_xor(d, 2);
  float rs = rsqrtf(d * 0.05f + LN_EPS);

  float un[5];
#pragma unroll
  for (int o = 0; o < 5; o++) {
    int j = q * 5 + o;
    un[o] = (h3[o] - mu) * rs * sB[60 + j] + sB[80 + j] + uu[j];  // +residual
  }
#pragma unroll
  for (int o = 0; o < 5; o++) u[(size_t)g * 20 + q * 5 + o] = un[o];

  if (has_next) {
    float ru[20];
#pragma unroll
    for (int k = 0; k < 20; k++)
      ru[k] = __shfl(un[k % 5], gl + (k / 5));
    float gn[5], gg[5];
#pragma unroll
    for (int o = 0; o < 5; o++) {
      int j = q * 5 + o;
      const v2f* wn = (const v2f*)(sNT + j * 20);
      const v2f* wg = (const v2f*)(sGT + j * 20);
      v2f an = {0.0f, 0.0f}, ag = {0.0f, 0.0f};
#pragma unroll
      for (int kk = 0; kk < 10; kk++) {
        v2f rv = {ru[2*kk], ru[2*kk+1]};
        an += rv * wn[kk];
        ag += rv * wg[kk];
      }
      gn[o] = sB[100 + j] + an.x + an.y;
      gg[o] = sB[120 + j] + ag.x + ag.y;
    }
#pragma unroll
    for (int o = 0; o < 5; o++) {
      gu[(size_t)g * 40 + q * 5 + o]      = gn[o];
      gu[(size_t)g * 40 + 20 + q * 5 + o] = gg[o];
    }
  }
}

// ---------------- host launcher ----------------

extern "C" void kernel_launch(void* const* d_in, const int* in_sizes, int n_in,
                              void* d_out, int out_size, void* d_ws, size_t ws_size,
                              hipStream_t stream) {
  const float* x_in  = (const float*)d_in[0];
  const int*   batch = (const int*)  d_in[1];
  const float* ni_W1 = (const float*)d_in[2];
  const float* ni_b1 = (const float*)d_in[3];
  const float* ni_W2 = (const float*)d_in[4];
  const float* ni_b2 = (const float*)d_in[5];
  const float* ni_W3 = (const float*)d_in[6];
  const float* ni_b3 = (const float*)d_in[7];
  const float* ni_g  = (const float*)d_in[8];
  const float* ni_be = (const float*)d_in[9];
  const float* nm_W1 = (const float*)d_in[10];
  const float* nm_b1 = (const float*)d_in[11];
  const float* nm_W2 = (const float*)d_in[12];
  const float* nm_b2 = (const float*)d_in[13];
  const float* nm_W3 = (const float*)d_in[14];
  const float* nm_b3 = (const float*)d_in[15];
  const float* nm_g  = (const float*)d_in[16];
  const float* nm_be = (const float*)d_in[17];
  const float* gp_W1 = (const float*)d_in[18];
  const float* gp_b1 = (const float*)d_in[19];
  const float* gp_W2 = (const float*)d_in[20];
  const float* gp_b2 = (const float*)d_in[21];
  const float* gp_W3 = (const float*)d_in[22];
  const float* gp_b3 = (const float*)d_in[23];
  const float* gp_g  = (const float*)d_in[24];
  const float* gp_be = (const float*)d_in[25];
  const float* gq_W1 = (const float*)d_in[26];
  const float* gq_b1 = (const float*)d_in[27];
  const float* gq_W2 = (const float*)d_in[28];
  const float* gq_b2 = (const float*)d_in[29];
  const float* gq_W3 = (const float*)d_in[30];
  const float* gq_b3 = (const float*)d_in[31];
  const float* gq_g  = (const float*)d_in[32];
  const float* gq_be = (const float*)d_in[33];

  const int N = in_sizes[0] / 10;          // 500000
  float* xs = (float*)d_out;               // x state in d_out[0 .. N*20)
  float* u  = xs + (size_t)N * 20;         // u in d_out tail (NG*20)

  float* part  = (float*)d_ws;             // NG*80 (4 slots x 20 per graph)
  float* gu    = part + NG * 80;           // NG*40 (merged nm|gp table)
  float* wpack = gu + NG * 40;             // L*2560 packed k_node weights

  const int L = 20;
  const int nblk = (N + 255) / 256;

  k_prelayer<<<(NG * 80) / 256, 256, 0, stream>>>(u, part, gu, nm_b1, gp_b1);
  k_pack<<<(L * 2560 + 255) / 256, 256, 0, stream>>>(wpack,
      nm_W1, nm_W2, nm_W3, nm_b2, nm_b3, nm_g, nm_be,
      gp_W1, gp_W2, gp_W3, gp_b2, gp_b3, gp_g, gp_be);
  k_init<<<nblk, 256, 0, stream>>>(x_in, xs, ni_W1, ni_b1, ni_W2, ni_b2,
                                   ni_W3, ni_b3, ni_g, ni_be, N);
  for (int l = 0; l < L; l++) {
    k_node<<<nblk, 256, 0, stream>>>(batch, xs, (float*)d_ws,
                                     wpack + (size_t)l * 2560, N);
    int has_next = (l < L - 1);
    k_global<<<(NG * 4) / 128, 128, 0, stream>>>(u, part, gu,
        gq_W1 + (size_t)l * 800, gq_b1 + l * 20,
        gq_W2 + (size_t)l * 400, gq_b2 + l * 20,
        gq_W3 + (size_t)l * 400, gq_b3 + l * 20,
        gq_g + l * 20, gq_be + l * 20,
        nm_W1 + (size_t)(l + 1) * 800 + 400, nm_b1 + (l + 1) * 20,
        gp_W1 + (size_t)(l + 1) * 800 + 400, gp_b1 + (l + 1) * 20,
        has_next);
  }
}